// Round 7
// baseline (1172.659 us; speedup 1.0000x reference)
//
#include <hip/hip_runtime.h>

#define BB 8
#define CC 384
#define HWP 50176
#define SS 256
#define MM 65536
#define TOPK 9
#define GM 2048          // BB*SS emb rows
#define NKC 16           // K-split blocks for segsum

typedef __attribute__((ext_vector_type(8))) __bf16 bf16x8;
typedef __attribute__((ext_vector_type(16))) float fx16;
typedef __attribute__((ext_vector_type(4))) float f32x4;

__device__ __forceinline__ unsigned short f2bf_rne(float x) {
    unsigned u = __float_as_uint(x);
    unsigned r = (u + 0x7FFFu + ((u >> 16) & 1u)) >> 16;
    return (unsigned short)r;
}

__device__ __forceinline__ bf16x8 pack8(float4 v0, float4 v1) {
    bf16x8 r;
    r[0] = (__bf16)v0.x; r[1] = (__bf16)v0.y; r[2] = (__bf16)v0.z; r[3] = (__bf16)v0.w;
    r[4] = (__bf16)v1.x; r[5] = (__bf16)v1.y; r[6] = (__bf16)v1.z; r[7] = (__bf16)v1.w;
    return r;
}

__device__ __forceinline__ void gl_lds16(const void* g, void* l) {
    auto gp = (const __attribute__((address_space(1))) unsigned int*)g;
    auto lp = (__attribute__((address_space(3))) unsigned int*)l;
    __builtin_amdgcn_global_load_lds(gp, lp, 16, 0, 0);
}

// ---------------- K1: per-batch label counts (parallel) ----------------
__global__ void k_counts2(const int* __restrict__ labels, unsigned* __restrict__ cntU) {
    __shared__ unsigned cnt[SS];
    int kc = blockIdx.x, b = blockIdx.y;   // (49, 8)
    int t = threadIdx.x;
    cnt[t] = 0u;
    __syncthreads();
    int4 lv = ((const int4*)(labels + (size_t)b * HWP + kc * 1024))[t];
    atomicAdd(&cnt[lv.x], 1u);
    atomicAdd(&cnt[lv.y], 1u);
    atomicAdd(&cnt[lv.z], 1u);
    atomicAdd(&cnt[lv.w], 1u);
    __syncthreads();
    if (cnt[t]) atomicAdd(&cntU[b * SS + t], cnt[t]);
}

// ---------------- K2: segment sums as one-hot MFMA GEMM, pipelined ----------------
template <bool ATOMIC>
__global__ __launch_bounds__(256) void k_segsum6(const float* __restrict__ feats,
                                                 const int* __restrict__ labels,
                                                 float* __restrict__ outp) {
    __shared__ bf16x8 Bs[8][64];
    __shared__ int labL[64];
    __shared__ unsigned smaskL[2];
    int kc = blockIdx.x, cg = blockIdx.y, b = blockIdx.z;
    int t = threadIdx.x, l = t & 63, w = t >> 6;
    int c0b = cg * 64;
    int c0w = c0b + w * 16;
    int g16 = l >> 4;
    int rowl = l & 15;

    f32x4 acc[16];
#pragma unroll
    for (int j = 0; j < 16; j++) acc[j] = (f32x4){0.f, 0.f, 0.f, 0.f};

    const float* fb = feats + ((size_t)b * CC + c0b) * HWP;
    const int* lbase = labels + (size_t)b * HWP + kc * 3136;

    int id0 = t * 2;
    int cl = id0 >> 3, g0 = id0 & 7;
    const float* tbase = fb + (size_t)cl * HWP + kc * 3136 + g0 * 8;

    float4 ra0 = *(const float4*)(tbase + 0);
    float4 ra1 = *(const float4*)(tbase + 4);
    float4 rb0 = *(const float4*)(tbase + 8);
    float4 rb1 = *(const float4*)(tbase + 12);
    int4 rl4 = (t < 16) ? ((const int4*)lbase)[t] : (int4){0, 0, 0, 0};

    if (t == 0) { smaskL[0] = 0u; smaskL[1] = 0u; }

    for (int tt = 0; tt < 49; tt++) {
        __syncthreads();
        if (t < 16) {
            ((int4*)labL)[t] = rl4;
            unsigned m = (1u << (rl4.x >> 4)) | (1u << (rl4.y >> 4)) |
                         (1u << (rl4.z >> 4)) | (1u << (rl4.w >> 4));
            atomicOr(&smaskL[tt & 1], m);
        }
        Bs[g0][cl] = pack8(ra0, ra1);
        Bs[g0 + 1][cl] = pack8(rb0, rb1);
        if (tt + 1 < 49) {
            const float* nb_ = tbase + (size_t)(tt + 1) * 64;
            ra0 = *(const float4*)(nb_ + 0);
            ra1 = *(const float4*)(nb_ + 4);
            rb0 = *(const float4*)(nb_ + 8);
            rb1 = *(const float4*)(nb_ + 12);
            if (t < 16) rl4 = ((const int4*)(lbase + (tt + 1) * 64))[t];
        }
        __syncthreads();
        unsigned sm = __builtin_amdgcn_readfirstlane(smaskL[tt & 1]);
        if (t == 0) smaskL[(tt + 1) & 1] = 0u;
        bf16x8 bf0 = Bs[g16][w * 16 + rowl];
        bf16x8 bf1 = Bs[4 + g16][w * 16 + rowl];
        int4 la0 = ((int4*)labL)[g16 * 2 + 0];
        int4 la1 = ((int4*)labL)[g16 * 2 + 1];
        int4 lb0 = ((int4*)labL)[8 + g16 * 2 + 0];
        int4 lb1 = ((int4*)labL)[8 + g16 * 2 + 1];
#pragma unroll
        for (int j = 0; j < 16; j++) {
            if (sm & (1u << j)) {
                int tgt = j * 16 + rowl;
                union { unsigned u[4]; bf16x8 v; } A;
                A.u[0] = (la0.x == tgt ? 0x3F80u : 0u) | (la0.y == tgt ? 0x3F800000u : 0u);
                A.u[1] = (la0.z == tgt ? 0x3F80u : 0u) | (la0.w == tgt ? 0x3F800000u : 0u);
                A.u[2] = (la1.x == tgt ? 0x3F80u : 0u) | (la1.y == tgt ? 0x3F800000u : 0u);
                A.u[3] = (la1.z == tgt ? 0x3F80u : 0u) | (la1.w == tgt ? 0x3F800000u : 0u);
                acc[j] = __builtin_amdgcn_mfma_f32_16x16x32_bf16(A.v, bf0, acc[j], 0, 0, 0);
                A.u[0] = (lb0.x == tgt ? 0x3F80u : 0u) | (lb0.y == tgt ? 0x3F800000u : 0u);
                A.u[1] = (lb0.z == tgt ? 0x3F80u : 0u) | (lb0.w == tgt ? 0x3F800000u : 0u);
                A.u[2] = (lb1.x == tgt ? 0x3F80u : 0u) | (lb1.y == tgt ? 0x3F800000u : 0u);
                A.u[3] = (lb1.z == tgt ? 0x3F80u : 0u) | (lb1.w == tgt ? 0x3F800000u : 0u);
                acc[j] = __builtin_amdgcn_mfma_f32_16x16x32_bf16(A.v, bf1, acc[j], 0, 0, 0);
            }
        }
    }
    if (ATOMIC) {
#pragma unroll
        for (int j = 0; j < 16; j++)
#pragma unroll
            for (int r = 0; r < 4; r++) {
                float v = acc[j][r];
                if (v != 0.f)
                    atomicAdd(&outp[((size_t)b * SS + j * 16 + g16 * 4 + r) * CC + c0w + rowl], v);
            }
    } else {
        float* dst = outp + (size_t)(kc * BB + b) * SS * CC;
#pragma unroll
        for (int j = 0; j < 16; j++)
#pragma unroll
            for (int r = 0; r < 4; r++)
                dst[(size_t)(j * 16 + g16 * 4 + r) * CC + c0w + rowl] = acc[j][r];
    }
}

// ---------------- K3: bank fp32->bf16 + row norms ----------------
__global__ void k_cvtmb(const float* __restrict__ mb, unsigned short* __restrict__ mbh,
                        float* __restrict__ yn) {
    int w = threadIdx.x >> 6, l = threadIdx.x & 63;
    int row = blockIdx.x * 4 + w;
    const float* r = mb + (size_t)row * CC;
    unsigned short* o = mbh + (size_t)row * CC;
    float s = 0.f;
#pragma unroll
    for (int i = 0; i < 6; i++) {
        float v = r[i * 64 + l];
        s = fmaf(v, v, s);
        o[i * 64 + l] = f2bf_rne(v);
    }
#pragma unroll
    for (int m = 32; m; m >>= 1) s += __shfl_xor(s, m);
    if (l == 0) yn[row] = s;
}

__global__ void k_ynorm(const float* __restrict__ mb, float* __restrict__ yn) {
    int w = threadIdx.x >> 6, l = threadIdx.x & 63;
    int row = blockIdx.x * 4 + w;
    const float* r = mb + (size_t)row * CC;
    float s = 0.f;
#pragma unroll
    for (int i = 0; i < 6; i++) { float v = r[i * 64 + l]; s = fmaf(v, v, s); }
#pragma unroll
    for (int m = 32; m; m >>= 1) s += __shfl_xor(s, m);
    if (l == 0) yn[row] = s;
}

// ---------------- K4a: reduce kc-partials -> emb + norms + bf16 copy ----------------
__global__ void k_embfin2(const float* __restrict__ kcpart, const unsigned* __restrict__ counts,
                          float* __restrict__ emb, float* __restrict__ xn,
                          unsigned short* __restrict__ embh) {
    int i = blockIdx.x;
    int b = i >> 8, s256 = i & 255;
    int l = threadIdx.x;
    float a6[6] = {0.f, 0.f, 0.f, 0.f, 0.f, 0.f};
    for (int kc = 0; kc < NKC; kc++) {
        const float* row = kcpart + ((size_t)(kc * BB + b) * SS + s256) * CC;
#pragma unroll
        for (int j = 0; j < 6; j++) a6[j] += row[j * 64 + l];
    }
    float inv = 1.f / fmaxf((float)counts[i], 1.f);
    float ss = 0.f;
#pragma unroll
    for (int j = 0; j < 6; j++) {
        float v = a6[j] * inv;
        emb[(size_t)i * CC + j * 64 + l] = v;
        embh[(size_t)i * CC + j * 64 + l] = f2bf_rne(v);
        ss = fmaf(v, v, ss);
    }
#pragma unroll
    for (int m = 32; m; m >>= 1) ss += __shfl_xor(ss, m);
    if (l == 0) xn[i] = ss;
}

// ---------------- K4b: finalize emb in place (lowmem path) ----------------
__global__ void k_embfin(float* __restrict__ emb, const unsigned* __restrict__ counts,
                         float* __restrict__ xn, unsigned short* __restrict__ embh) {
    int i = blockIdx.x, l = threadIdx.x;
    float inv = 1.f / fmaxf((float)counts[i], 1.f);
    float* e = emb + (size_t)i * CC;
    unsigned short* o = embh + (size_t)i * CC;
    float s = 0.f;
#pragma unroll
    for (int j = 0; j < 6; j++) {
        float v = e[j * 64 + l] * inv;
        e[j * 64 + l] = v;
        o[j * 64 + l] = f2bf_rne(v);
        s = fmaf(v, v, s);
    }
#pragma unroll
    for (int m = 32; m; m >>= 1) s += __shfl_xor(s, m);
    if (l == 0) xn[i] = s;
}

// ---------------- K5: 256x256 bf16 MFMA GEMM + fused row-min (u32 keys) ----------------
// 2048 blocks x 512 thr (8 waves, 2M x 4N; wave-tile 128x64).
// key u32 = (d2_bits & ~0xFF) | col_local(8b): d2 truncation <= 0.012 abs (score ~3e-4),
// exact refine recomputes critical candidates. Partials u32, expanded at reduce1.
template <bool REGB>
__global__ __launch_bounds__(512) void k_gemm256(
        const unsigned short* __restrict__ Ah, const unsigned short* __restrict__ Bh,
        const float* __restrict__ Bf,
        const float* __restrict__ xn, const float* __restrict__ yn,
        unsigned* __restrict__ partials) {
    __shared__ bf16x8 As[8][256];
    __shared__ bf16x8 Bs[8][256];
    __shared__ unsigned rowbest[256];
    int bid = blockIdx.x;
    int swz = (bid & 7) * 256 + (bid >> 3);   // bijective: 2048 % 8 == 0
    int rb = swz & 7, nb = swz >> 3;
    int t = threadIdx.x;
    int w = t >> 6, l = t & 63;
    int wm = w >> 2, wn = w & 3;

    if (t < 256) rowbest[t] = 0xFFFFFFFFu;

    fx16 acc[4][2];
#pragma unroll
    for (int i = 0; i < 4; i++)
#pragma unroll
        for (int n = 0; n < 2; n++)
#pragma unroll
            for (int p = 0; p < 16; p++) acc[i][n][p] = 0.f;

    const unsigned short* Abase = Ah + (size_t)(rb * 256) * CC;
    const unsigned short* Bbase = REGB ? nullptr : (Bh + (size_t)(nb * 256) * CC);
    const float* Bfbase = Bf + (size_t)(nb * 256) * CC;

    for (int kt = 0; kt < 6; kt++) {
        int k0 = kt * 64;
#pragma unroll
        for (int q = 0; q < 4; q++) {
            int c = q * 512 + t;
            int r = c & 255, g = c >> 8;
            gl_lds16(Abase + (size_t)r * CC + k0 + g * 8, &As[g][r]);
            if (!REGB) {
                gl_lds16(Bbase + (size_t)r * CC + k0 + g * 8, &Bs[g][r]);
            } else {
                const float* src = Bfbase + (size_t)r * CC + k0 + g * 8;
                float4 v0 = *(const float4*)(src);
                float4 v1 = *(const float4*)(src + 4);
                Bs[g][r] = pack8(v0, v1);
            }
        }
        __syncthreads();
#pragma unroll
        for (int ks = 0; ks < 4; ks++) {
            int g = ks * 2 + (l >> 5);
            bf16x8 b0 = Bs[g][wn * 64 + (l & 31)];
            bf16x8 b1 = Bs[g][wn * 64 + 32 + (l & 31)];
#pragma unroll
            for (int i = 0; i < 4; i++) {
                bf16x8 a = As[g][wm * 128 + i * 32 + (l & 31)];
                acc[i][0] = __builtin_amdgcn_mfma_f32_32x32x16_bf16(a, b0, acc[i][0], 0, 0, 0);
                acc[i][1] = __builtin_amdgcn_mfma_f32_32x32x16_bf16(a, b1, acc[i][1], 0, 0, 0);
            }
        }
        __syncthreads();
    }

    float yn0 = yn[nb * 256 + wn * 64 + (l & 31)];
    float yn1 = yn[nb * 256 + wn * 64 + 32 + (l & 31)];
#pragma unroll
    for (int i = 0; i < 4; i++) {
#pragma unroll
        for (int p = 0; p < 16; p++) {
            int rl = wm * 128 + i * 32 + (p & 3) + 8 * (p >> 2) + 4 * (l >> 5);
            float xr = xn[rb * 256 + rl];
            float d0 = fmaxf(xr - 2.f * acc[i][0][p] + yn0, 0.f);
            float d1 = fmaxf(xr - 2.f * acc[i][1][p] + yn1, 0.f);
            unsigned k0 = (__float_as_uint(d0) & 0xFFFFFF00u) | (unsigned)(wn * 64 + (l & 31));
            unsigned k1 = (__float_as_uint(d1) & 0xFFFFFF00u) | (unsigned)(wn * 64 + 32 + (l & 31));
            unsigned best = k0 < k1 ? k0 : k1;
#pragma unroll
            for (int m = 1; m < 32; m <<= 1) {
                unsigned o2 = __shfl_xor(best, m);
                if (o2 < best) best = o2;
            }
            if ((l & 31) == 0) atomicMin(&rowbest[rl], best);
        }
    }
    __syncthreads();
    if (t < 256) partials[(size_t)nb * GM + rb * 256 + t] = rowbest[t];
}

// ---------------- K6: expand u32 keys -> u64 global, min over 32 nb ----------------
__global__ void k_reduce1(const unsigned* __restrict__ partials,
                          unsigned long long* __restrict__ partial2) {
    int row = blockIdx.x * 256 + threadIdx.x;
    int ng = blockIdx.y;
    unsigned long long m = ~0ull;
    for (int n = 0; n < 32; n++) {
        int nb = ng * 32 + n;
        unsigned k = partials[(size_t)nb * GM + row];
        unsigned long long v = ((unsigned long long)(k & 0xFFFFFF00u) << 32)
                             | (unsigned)(nb * 256 + (k & 0xFFu));
        if (v < m) m = v;
    }
    partial2[ng * GM + row] = m;
}

// ---------------- K7: final min + scores + per-batch top-4 candidates ----------------
__global__ void k_reduce2cand(const unsigned long long* __restrict__ partial2,
                              float* __restrict__ scores, int* __restrict__ locs,
                              int* __restrict__ cand) {
    __shared__ unsigned long long key[256];
    __shared__ unsigned long long red[256];
    int b = blockIdx.x, t = threadIdx.x;
    int row = b * 256 + t;
    unsigned long long m = ~0ull;
    for (int g = 0; g < 8; g++) {
        unsigned long long v = partial2[g * GM + row];
        if (v < m) m = v;
    }
    float sc = sqrtf(__uint_as_float((unsigned)(m >> 32)));
    scores[row] = sc;
    locs[row] = (int)(m & 0xffffffffu);
    key[t] = ((unsigned long long)__float_as_uint(sc) << 32) | (unsigned)(255 - t);
    __syncthreads();
    for (int k = 0; k < 4; k++) {
        red[t] = key[t];
        __syncthreads();
        for (int s = 128; s; s >>= 1) {
            if (t < s && red[t + s] > red[t]) red[t] = red[t + s];
            __syncthreads();
        }
        unsigned long long win = red[0];
        int patch = 255 - (int)(win & 0xffffffffu);
        if (t == 0) cand[b * 4 + k] = b * SS + patch;
        __syncthreads();
        if (t == patch) key[t] = 0;
        __syncthreads();
    }
}

// ---------------- K9: exact fp32 re-search for 32 candidate rows ----------------
#define RF_ROWS 8
__global__ __launch_bounds__(256) void k_refine(
        const float* __restrict__ emb, const float* __restrict__ mb,
        const float* __restrict__ xn, const float* __restrict__ yn,
        const int* __restrict__ cand, unsigned long long* __restrict__ refpart) {
    __shared__ float cl[32 * CC];
    __shared__ float xnc[32];
    __shared__ int cr[32];
    __shared__ unsigned long long bmin[32];
    int t = threadIdx.x;
    if (t < 32) cr[t] = cand[t];
    __syncthreads();
    if (t < 32) { xnc[t] = xn[cr[t]]; bmin[t] = ~0ull; }
    for (int i = t; i < 32 * CC; i += 256) {
        int j = i / CC, p = i - j * CC;
        cl[i] = emb[(size_t)cr[j] * CC + p];
    }
    __syncthreads();
    int w = t >> 6, l = t & 63;
    int m0 = blockIdx.x * RF_ROWS + w * 2, m1 = m0 + 1;
    float2 r0[3], r1[3];
#pragma unroll
    for (int c = 0; c < 3; c++) {
        r0[c] = *(const float2*)&mb[(size_t)m0 * CC + c * 128 + l * 2];
        r1[c] = *(const float2*)&mb[(size_t)m1 * CC + c * 128 + l * 2];
    }
    float ya = yn[m0], yb = yn[m1];
    for (int j = 0; j < 32; j++) {
        float s0 = 0.f, s1 = 0.f;
#pragma unroll
        for (int c = 0; c < 3; c++) {
            float2 cv = *(const float2*)&cl[j * CC + c * 128 + l * 2];
            s0 = fmaf(r0[c].x, cv.x, s0); s0 = fmaf(r0[c].y, cv.y, s0);
            s1 = fmaf(r1[c].x, cv.x, s1); s1 = fmaf(r1[c].y, cv.y, s1);
        }
#pragma unroll
        for (int mm = 32; mm; mm >>= 1) { s0 += __shfl_xor(s0, mm); s1 += __shfl_xor(s1, mm); }
        if (l == 0) {
            float d0 = fmaxf(xnc[j] - 2.f * s0 + ya, 0.f);
            float d1 = fmaxf(xnc[j] - 2.f * s1 + yb, 0.f);
            unsigned long long k0 = ((unsigned long long)__float_as_uint(d0) << 32) | (unsigned)m0;
            unsigned long long k1 = ((unsigned long long)__float_as_uint(d1) << 32) | (unsigned)m1;
            unsigned long long kb = k0 < k1 ? k0 : k1;
            atomicMin(&bmin[j], kb);
        }
    }
    __syncthreads();
    if (t < 32) refpart[(size_t)blockIdx.x * 32 + t] = bmin[t];
}

__global__ void k_refred(const unsigned long long* __restrict__ refpart,
                         unsigned long long* __restrict__ keys2) {
    __shared__ unsigned long long red[256];
    int j = blockIdx.x, t = threadIdx.x;
    unsigned long long m = ~0ull;
    for (int i = t; i < MM / RF_ROWS; i += 256) {
        unsigned long long v = refpart[(size_t)i * 32 + j];
        if (v < m) m = v;
    }
    red[t] = m;
    __syncthreads();
    for (int s = 128; s; s >>= 1) {
        if (t < s && red[t + s] < red[t]) red[t] = red[t + s];
        __syncthreads();
    }
    if (t == 0) keys2[j] = red[0];
}

__global__ void k_final(const unsigned long long* __restrict__ keys2, const int* __restrict__ cand,
                        int* __restrict__ mp, float* __restrict__ scb, int* __restrict__ nn) {
    int b = threadIdx.x;
    if (b < BB) {
        float bestsc = -1.f;
        int bestpatch = 1 << 20, bestnn = 0;
        for (int k = 0; k < 4; k++) {
            unsigned long long key = keys2[b * 4 + k];
            float sc = sqrtf(__uint_as_float((unsigned)(key >> 32)));
            int patch = cand[b * 4 + k] & 255;
            int nnidx = (int)(key & 0xffffffffu);
            if (sc > bestsc || (sc == bestsc && patch < bestpatch)) {
                bestsc = sc; bestpatch = patch; bestnn = nnidx;
            }
        }
        mp[b] = bestpatch; scb[b] = bestsc; nn[b] = bestnn;
    }
}

// ---------------- K12: d_nn ----------------
__global__ void k_dnn(const float* __restrict__ mb, const float* __restrict__ yn,
                      const int* __restrict__ nn, float* __restrict__ dnn) {
    __shared__ float nnf[BB][CC];
    int t = threadIdx.x;
    for (int i = t; i < BB * CC; i += 256) {
        int bb = i / CC, cc = i % CC;
        nnf[bb][cc] = mb[(size_t)nn[bb] * CC + cc];
    }
    __syncthreads();
    int w = t >> 6, l = t & 63;
    int m = blockIdx.x * 4 + w;
    float accv[BB];
#pragma unroll
    for (int b = 0; b < BB; b++) accv[b] = 0.f;
    const float* r = mb + (size_t)m * CC;
#pragma unroll
    for (int i = 0; i < 6; i++) {
        float v = r[i * 64 + l];
#pragma unroll
        for (int b = 0; b < BB; b++) accv[b] = fmaf(v, nnf[b][i * 64 + l], accv[b]);
    }
#pragma unroll
    for (int b = 0; b < BB; b++) {
        float s = accv[b];
#pragma unroll
        for (int mm = 32; mm; mm >>= 1) s += __shfl_xor(s, mm);
        if (l == 0) {
            float d2 = fmaxf(yn[nn[b]] - 2.f * s + yn[m], 0.f);
            dnn[(size_t)b * MM + m] = sqrtf(d2);
        }
    }
}

// ---------------- K13: top-9 ----------------
__global__ void k_top9(const float* __restrict__ dnn, int* __restrict__ sup) {
    __shared__ float sd[256][TOPK];
    __shared__ int sx[256][TOPK];
    int b = blockIdx.x, t = threadIdx.x;
    float ld[TOPK];
    int li[TOPK];
#pragma unroll
    for (int k = 0; k < TOPK; k++) { ld[k] = INFINITY; li[k] = MM; }
    const float* d = dnn + (size_t)b * MM;
    for (int m = t; m < MM; m += 256) {
        float v = d[m];
        if (v < ld[TOPK - 1] || (v == ld[TOPK - 1] && m < li[TOPK - 1])) {
            int k = TOPK - 1;
            while (k > 0 && (v < ld[k - 1] || (v == ld[k - 1] && m < li[k - 1]))) {
                ld[k] = ld[k - 1]; li[k] = li[k - 1]; k--;
            }
            ld[k] = v; li[k] = m;
        }
    }
    for (int k = 0; k < TOPK; k++) { sd[t][k] = ld[k]; sx[t][k] = li[k]; }
    __syncthreads();
    for (int s = 128; s; s >>= 1) {
        if (t < s) {
            float md[TOPK]; int mi[TOPK];
            int p = 0, q = 0;
            for (int k = 0; k < TOPK; k++) {
                float va = sd[t][p], vb = sd[t + s][q];
                int ia = sx[t][p], ib = sx[t + s][q];
                bool ta = (va < vb) || (va == vb && ia < ib);
                if (ta) { md[k] = va; mi[k] = ia; p++; }
                else    { md[k] = vb; mi[k] = ib; q++; }
            }
            for (int k = 0; k < TOPK; k++) { sd[t][k] = md[k]; sx[t][k] = mi[k]; }
        }
        __syncthreads();
    }
    if (t < TOPK) sup[b * TOPK + t] = sx[0][t];
}

// ---------------- K14: pred_score ----------------
__global__ void k_pred(const float* __restrict__ emb, const float* __restrict__ mb,
                       const float* __restrict__ yn, const float* __restrict__ xn,
                       const int* __restrict__ mp, const float* __restrict__ scb,
                       const int* __restrict__ sup, float* __restrict__ outp) {
    __shared__ float ds[TOPK];
    int b = blockIdx.x;
    int t = threadIdx.x;
    int w = t >> 6, l = t & 63;
    int mpb = mp[b];
    const float* mf = emb + ((size_t)b * SS + mpb) * CC;
    float xr = xn[b * SS + mpb];
    for (int k = w; k < TOPK; k += 4) {
        int sidx = sup[b * TOPK + k];
        const float* sr = mb + (size_t)sidx * CC;
        float s = 0.f;
#pragma unroll
        for (int i = 0; i < 6; i++) s = fmaf(mf[i * 64 + l], sr[i * 64 + l], s);
#pragma unroll
        for (int mm = 32; mm; mm >>= 1) s += __shfl_xor(s, mm);
        if (l == 0) ds[k] = sqrtf(fmaxf(xr - 2.f * s + yn[sidx], 0.f));
    }
    __syncthreads();
    if (t == 0) {
        float mx = ds[0];
        for (int k = 1; k < TOPK; k++) mx = fmaxf(mx, ds[k]);
        float num = expf(ds[0] - mx), den = 0.f;
        for (int k = 0; k < TOPK; k++) den += expf(ds[k] - mx);
        outp[b] = (1.f - num / den) * scb[b];
    }
}

// ---------------- K15: anomaly map scatter ----------------
__global__ void k_map(const float* __restrict__ scores, const int* __restrict__ labels,
                      float* __restrict__ out) {
    size_t i = (size_t)blockIdx.x * 256 + threadIdx.x;
    int b = (int)(i / HWP);
    out[i] = scores[b * SS + labels[i]];
}

extern "C" void kernel_launch(void* const* d_in, const int* in_sizes, int n_in,
                              void* d_out, int out_size, void* d_ws, size_t ws_size,
                              hipStream_t stream) {
    const float* feats  = (const float*)d_in[0];
    const int*   labels = (const int*)d_in[1];
    const float* mb     = (const float*)d_in[2];
    float* out = (float*)d_out;

    char* ws = (char*)d_ws;
    const size_t SZ_MBH   = (size_t)MM * CC * 2;              // 50.3 MB
    const size_t SZ_EMBH  = (size_t)GM * CC * 2;
    const size_t SZ_EMB   = (size_t)GM * CC * 4;
    const size_t SZ_YN    = (size_t)MM * 4;
    const size_t SZ_SMALL = 8192;
    const size_t SZ_P2    = (size_t)8 * GM * 8;
    const size_t SZ_KCP   = (size_t)NKC * BB * SS * CC * 4;   // 50.3 MB kc-partials
    const size_t SZ_BIG   = SZ_KCP;                           // also holds partials/refpart/dnn later

    size_t need_full = SZ_MBH + SZ_EMBH + SZ_EMB + SZ_YN + 4 * SZ_SMALL + 2048 + SZ_P2 + SZ_BIG + 512;
    bool lowmem = ws_size < need_full;

    size_t o = 0;
    unsigned short* mbh = nullptr;
    if (!lowmem) { mbh = (unsigned short*)(ws + o); o += SZ_MBH; }
    unsigned short* embh = (unsigned short*)(ws + o); o += SZ_EMBH;
    float* emb = (float*)(ws + o);                    o += SZ_EMB;
    float* yn  = (float*)(ws + o);                    o += SZ_YN;
    float* xn  = (float*)(ws + o);                    o += SZ_SMALL;
    unsigned* cntU = (unsigned*)(ws + o);             o += SZ_SMALL;
    float* scores = (float*)(ws + o);                 o += SZ_SMALL;
    int*   locs   = (int*)(ws + o);                   o += SZ_SMALL;
    int*   cand   = (int*)(ws + o);                   o += 256;
    unsigned long long* keys2 = (unsigned long long*)(ws + o); o += 256;
    int*   mp  = (int*)(ws + o);                      o += 128;
    float* scb = (float*)(ws + o);                    o += 128;
    int*   nn  = (int*)(ws + o);                      o += 128;
    int*   sup = (int*)(ws + o);                      o += 512;
    o = (o + 255) & ~(size_t)255;
    unsigned long long* partial2 = (unsigned long long*)(ws + o); o += SZ_P2;
    char* big = ws + o;
    float* kcpart = (float*)big;                                   // segsum partials (consumed by embfin2)
    unsigned* partials = (unsigned*)big;                           // gemm u32 partials (after kcpart dead)
    unsigned long long* refpart  = (unsigned long long*)big;       // after partials consumed
    float* dnn = (float*)(big + 4194304);                          // disjoint from refpart (2 MB)

    hipMemsetAsync(cntU, 0, (size_t)GM * 4, stream);
    k_counts2<<<dim3(49, BB), 256, 0, stream>>>(labels, cntU);

    if (!lowmem) {
        k_segsum6<false><<<dim3(NKC, 6, BB), 256, 0, stream>>>(feats, labels, kcpart);
        k_cvtmb<<<MM / 4, 256, 0, stream>>>(mb, mbh, yn);
        k_embfin2<<<GM, 64, 0, stream>>>(kcpart, cntU, emb, xn, embh);
        k_gemm256<false><<<2048, 512, 0, stream>>>(embh, mbh, mb, xn, yn, partials);
    } else {
        hipMemsetAsync(emb, 0, SZ_EMB, stream);
        k_segsum6<true><<<dim3(NKC, 6, BB), 256, 0, stream>>>(feats, labels, emb);
        k_ynorm<<<MM / 4, 256, 0, stream>>>(mb, yn);
        k_embfin<<<GM, 64, 0, stream>>>(emb, cntU, xn, embh);
        k_gemm256<true><<<2048, 512, 0, stream>>>(embh, embh, mb, xn, yn, partials);
    }

    k_reduce1<<<dim3(8, 8), 256, 0, stream>>>(partials, partial2);
    k_reduce2cand<<<BB, 256, 0, stream>>>(partial2, scores, locs, cand);
    k_refine<<<MM / RF_ROWS, 256, 0, stream>>>(emb, mb, xn, yn, cand, refpart);
    k_refred<<<32, 256, 0, stream>>>(refpart, keys2);
    k_final<<<1, 64, 0, stream>>>(keys2, cand, mp, scb, nn);
    k_dnn<<<MM / 4, 256, 0, stream>>>(mb, yn, nn, dnn);
    k_top9<<<BB, 256, 0, stream>>>(dnn, sup);
    k_pred<<<BB, 256, 0, stream>>>(emb, mb, yn, xn, mp, scb, sup, out + (size_t)BB * HWP);
    k_map<<<(BB * HWP) / 256, 256, 0, stream>>>(scores, labels, out);
}

// Round 8
// 858.587 us; speedup vs baseline: 1.3658x; 1.3658x over previous
//
#include <hip/hip_runtime.h>

#define BB 8
#define CC 384
#define HWP 50176
#define SS 256
#define MM 65536
#define TOPK 9
#define GM 2048          // BB*SS emb rows
#define NKC 16           // K-split blocks for segsum

typedef __attribute__((ext_vector_type(8))) __bf16 bf16x8;
typedef __attribute__((ext_vector_type(16))) float fx16;
typedef __attribute__((ext_vector_type(4))) float f32x4;

__device__ __forceinline__ unsigned short f2bf_rne(float x) {
    unsigned u = __float_as_uint(x);
    unsigned r = (u + 0x7FFFu + ((u >> 16) & 1u)) >> 16;
    return (unsigned short)r;
}

__device__ __forceinline__ bf16x8 pack8(float4 v0, float4 v1) {
    bf16x8 r;
    r[0] = (__bf16)v0.x; r[1] = (__bf16)v0.y; r[2] = (__bf16)v0.z; r[3] = (__bf16)v0.w;
    r[4] = (__bf16)v1.x; r[5] = (__bf16)v1.y; r[6] = (__bf16)v1.z; r[7] = (__bf16)v1.w;
    return r;
}

__device__ __forceinline__ void gl_lds16(const void* g, void* l) {
    auto gp = (const __attribute__((address_space(1))) unsigned int*)g;
    auto lp = (__attribute__((address_space(3))) unsigned int*)l;
    __builtin_amdgcn_global_load_lds(gp, lp, 16, 0, 0);
}

// ---------------- K1: per-batch label counts (parallel) ----------------
__global__ void k_counts2(const int* __restrict__ labels, unsigned* __restrict__ cntU) {
    __shared__ unsigned cnt[SS];
    int kc = blockIdx.x, b = blockIdx.y;   // (49, 8)
    int t = threadIdx.x;
    cnt[t] = 0u;
    __syncthreads();
    int4 lv = ((const int4*)(labels + (size_t)b * HWP + kc * 1024))[t];
    atomicAdd(&cnt[lv.x], 1u);
    atomicAdd(&cnt[lv.y], 1u);
    atomicAdd(&cnt[lv.z], 1u);
    atomicAdd(&cnt[lv.w], 1u);
    __syncthreads();
    if (cnt[t]) atomicAdd(&cntU[b * SS + t], cnt[t]);
}

// ---------------- K2: segment sums as one-hot MFMA GEMM, pipelined ----------------
template <bool ATOMIC>
__global__ __launch_bounds__(256) void k_segsum6(const float* __restrict__ feats,
                                                 const int* __restrict__ labels,
                                                 float* __restrict__ outp) {
    __shared__ bf16x8 Bs[8][64];
    __shared__ int labL[64];
    __shared__ unsigned smaskL[2];
    int kc = blockIdx.x, cg = blockIdx.y, b = blockIdx.z;
    int t = threadIdx.x, l = t & 63, w = t >> 6;
    int c0b = cg * 64;
    int c0w = c0b + w * 16;
    int g16 = l >> 4;
    int rowl = l & 15;

    f32x4 acc[16];
#pragma unroll
    for (int j = 0; j < 16; j++) acc[j] = (f32x4){0.f, 0.f, 0.f, 0.f};

    const float* fb = feats + ((size_t)b * CC + c0b) * HWP;
    const int* lbase = labels + (size_t)b * HWP + kc * 3136;

    int id0 = t * 2;
    int cl = id0 >> 3, g0 = id0 & 7;
    const float* tbase = fb + (size_t)cl * HWP + kc * 3136 + g0 * 8;

    float4 ra0 = *(const float4*)(tbase + 0);
    float4 ra1 = *(const float4*)(tbase + 4);
    float4 rb0 = *(const float4*)(tbase + 8);
    float4 rb1 = *(const float4*)(tbase + 12);
    int4 rl4 = (t < 16) ? ((const int4*)lbase)[t] : (int4){0, 0, 0, 0};

    if (t == 0) { smaskL[0] = 0u; smaskL[1] = 0u; }

    for (int tt = 0; tt < 49; tt++) {
        __syncthreads();
        if (t < 16) {
            ((int4*)labL)[t] = rl4;
            unsigned m = (1u << (rl4.x >> 4)) | (1u << (rl4.y >> 4)) |
                         (1u << (rl4.z >> 4)) | (1u << (rl4.w >> 4));
            atomicOr(&smaskL[tt & 1], m);
        }
        Bs[g0][cl] = pack8(ra0, ra1);
        Bs[g0 + 1][cl] = pack8(rb0, rb1);
        if (tt + 1 < 49) {
            const float* nb_ = tbase + (size_t)(tt + 1) * 64;
            ra0 = *(const float4*)(nb_ + 0);
            ra1 = *(const float4*)(nb_ + 4);
            rb0 = *(const float4*)(nb_ + 8);
            rb1 = *(const float4*)(nb_ + 12);
            if (t < 16) rl4 = ((const int4*)(lbase + (tt + 1) * 64))[t];
        }
        __syncthreads();
        unsigned sm = __builtin_amdgcn_readfirstlane(smaskL[tt & 1]);
        if (t == 0) smaskL[(tt + 1) & 1] = 0u;
        bf16x8 bf0 = Bs[g16][w * 16 + rowl];
        bf16x8 bf1 = Bs[4 + g16][w * 16 + rowl];
        int4 la0 = ((int4*)labL)[g16 * 2 + 0];
        int4 la1 = ((int4*)labL)[g16 * 2 + 1];
        int4 lb0 = ((int4*)labL)[8 + g16 * 2 + 0];
        int4 lb1 = ((int4*)labL)[8 + g16 * 2 + 1];
#pragma unroll
        for (int j = 0; j < 16; j++) {
            if (sm & (1u << j)) {
                int tgt = j * 16 + rowl;
                union { unsigned u[4]; bf16x8 v; } A;
                A.u[0] = (la0.x == tgt ? 0x3F80u : 0u) | (la0.y == tgt ? 0x3F800000u : 0u);
                A.u[1] = (la0.z == tgt ? 0x3F80u : 0u) | (la0.w == tgt ? 0x3F800000u : 0u);
                A.u[2] = (la1.x == tgt ? 0x3F80u : 0u) | (la1.y == tgt ? 0x3F800000u : 0u);
                A.u[3] = (la1.z == tgt ? 0x3F80u : 0u) | (la1.w == tgt ? 0x3F800000u : 0u);
                acc[j] = __builtin_amdgcn_mfma_f32_16x16x32_bf16(A.v, bf0, acc[j], 0, 0, 0);
                A.u[0] = (lb0.x == tgt ? 0x3F80u : 0u) | (lb0.y == tgt ? 0x3F800000u : 0u);
                A.u[1] = (lb0.z == tgt ? 0x3F80u : 0u) | (lb0.w == tgt ? 0x3F800000u : 0u);
                A.u[2] = (lb1.x == tgt ? 0x3F80u : 0u) | (lb1.y == tgt ? 0x3F800000u : 0u);
                A.u[3] = (lb1.w == tgt ? 0x3F800000u : 0u) | (lb1.z == tgt ? 0x3F80u : 0u);
                acc[j] = __builtin_amdgcn_mfma_f32_16x16x32_bf16(A.v, bf1, acc[j], 0, 0, 0);
            }
        }
    }
    if (ATOMIC) {
#pragma unroll
        for (int j = 0; j < 16; j++)
#pragma unroll
            for (int r = 0; r < 4; r++) {
                float v = acc[j][r];
                if (v != 0.f)
                    atomicAdd(&outp[((size_t)b * SS + j * 16 + g16 * 4 + r) * CC + c0w + rowl], v);
            }
    } else {
        float* dst = outp + (size_t)(kc * BB + b) * SS * CC;
#pragma unroll
        for (int j = 0; j < 16; j++)
#pragma unroll
            for (int r = 0; r < 4; r++)
                dst[(size_t)(j * 16 + g16 * 4 + r) * CC + c0w + rowl] = acc[j][r];
    }
}

// ---------------- K3: bank fp32->bf16 + row norms ----------------
__global__ void k_cvtmb(const float* __restrict__ mb, unsigned short* __restrict__ mbh,
                        float* __restrict__ yn) {
    int w = threadIdx.x >> 6, l = threadIdx.x & 63;
    int row = blockIdx.x * 4 + w;
    const float* r = mb + (size_t)row * CC;
    unsigned short* o = mbh + (size_t)row * CC;
    float s = 0.f;
#pragma unroll
    for (int i = 0; i < 6; i++) {
        float v = r[i * 64 + l];
        s = fmaf(v, v, s);
        o[i * 64 + l] = f2bf_rne(v);
    }
#pragma unroll
    for (int m = 32; m; m >>= 1) s += __shfl_xor(s, m);
    if (l == 0) yn[row] = s;
}

__global__ void k_ynorm(const float* __restrict__ mb, float* __restrict__ yn) {
    int w = threadIdx.x >> 6, l = threadIdx.x & 63;
    int row = blockIdx.x * 4 + w;
    const float* r = mb + (size_t)row * CC;
    float s = 0.f;
#pragma unroll
    for (int i = 0; i < 6; i++) { float v = r[i * 64 + l]; s = fmaf(v, v, s); }
#pragma unroll
    for (int m = 32; m; m >>= 1) s += __shfl_xor(s, m);
    if (l == 0) yn[row] = s;
}

// ---------------- K4a: reduce kc-partials -> emb + norms + bf16 copy ----------------
__global__ void k_embfin2(const float* __restrict__ kcpart, const unsigned* __restrict__ counts,
                          float* __restrict__ emb, float* __restrict__ xn,
                          unsigned short* __restrict__ embh) {
    int i = blockIdx.x;
    int b = i >> 8, s256 = i & 255;
    int l = threadIdx.x;
    float a6[6] = {0.f, 0.f, 0.f, 0.f, 0.f, 0.f};
    for (int kc = 0; kc < NKC; kc++) {
        const float* row = kcpart + ((size_t)(kc * BB + b) * SS + s256) * CC;
#pragma unroll
        for (int j = 0; j < 6; j++) a6[j] += row[j * 64 + l];
    }
    float inv = 1.f / fmaxf((float)counts[i], 1.f);
    float ss = 0.f;
#pragma unroll
    for (int j = 0; j < 6; j++) {
        float v = a6[j] * inv;
        emb[(size_t)i * CC + j * 64 + l] = v;
        embh[(size_t)i * CC + j * 64 + l] = f2bf_rne(v);
        ss = fmaf(v, v, ss);
    }
#pragma unroll
    for (int m = 32; m; m >>= 1) ss += __shfl_xor(ss, m);
    if (l == 0) xn[i] = ss;
}

// ---------------- K4b: finalize emb in place (lowmem path) ----------------
__global__ void k_embfin(float* __restrict__ emb, const unsigned* __restrict__ counts,
                         float* __restrict__ xn, unsigned short* __restrict__ embh) {
    int i = blockIdx.x, l = threadIdx.x;
    float inv = 1.f / fmaxf((float)counts[i], 1.f);
    float* e = emb + (size_t)i * CC;
    unsigned short* o = embh + (size_t)i * CC;
    float s = 0.f;
#pragma unroll
    for (int j = 0; j < 6; j++) {
        float v = e[j * 64 + l] * inv;
        e[j * 64 + l] = v;
        o[j * 64 + l] = f2bf_rne(v);
        s = fmaf(v, v, s);
    }
#pragma unroll
    for (int m = 32; m; m >>= 1) s += __shfl_xor(s, m);
    if (l == 0) xn[i] = s;
}

// ---------------- K5: 128x128 bf16 MFMA GEMM + fused row-min (u32 keys) ----------------
// 8192 blocks x 256 thr (4 waves, 64-AGPR acc -> ~3 blocks/CU).
// key u32 = (d2_bits & ~0xFF) | col_local(7b). d2 truncation 0.016 abs -> score 3e-4;
// argmin shifts only matter at max patch, recomputed exactly by k_refine.
template <bool REGB>
__global__ __launch_bounds__(256) void k_gemm(
        const unsigned short* __restrict__ Ah, const unsigned short* __restrict__ Bh,
        const float* __restrict__ Bf,
        const float* __restrict__ xn, const float* __restrict__ yn,
        unsigned* __restrict__ partials) {
    __shared__ bf16x8 As[8][128];
    __shared__ bf16x8 Bs[8][128];
    __shared__ unsigned rowbest[128];
    int bid = blockIdx.x;
    int swz = (bid & 7) * 1024 + (bid >> 3);   // bijective: 8192 % 8 == 0
    int rb = swz & 15, nb = swz >> 4;
    int t = threadIdx.x;
    int w = t >> 6, l = t & 63;
    int wm = w & 1, wn = w >> 1;

    if (t < 128) rowbest[t] = 0xFFFFFFFFu;

    fx16 acc00, acc01, acc10, acc11;
#pragma unroll
    for (int p = 0; p < 16; p++) { acc00[p] = 0.f; acc01[p] = 0.f; acc10[p] = 0.f; acc11[p] = 0.f; }

    const unsigned short* Abase = Ah + (size_t)(rb * 128) * CC;
    const unsigned short* Bbase = REGB ? nullptr : (Bh + (size_t)(nb * 128) * CC);
    const float* Bfbase = Bf + (size_t)(nb * 128) * CC;

    for (int kt = 0; kt < 6; kt++) {
        int k0 = kt * 64;
#pragma unroll
        for (int q = 0; q < 4; q++) {
            int c = q * 256 + t;
            int r = c & 127, g = c >> 7;
            gl_lds16(Abase + (size_t)r * CC + k0 + g * 8, &As[g][r]);
            if (!REGB) {
                gl_lds16(Bbase + (size_t)r * CC + k0 + g * 8, &Bs[g][r]);
            } else {
                const float* src = Bfbase + (size_t)r * CC + k0 + g * 8;
                float4 v0 = *(const float4*)(src);
                float4 v1 = *(const float4*)(src + 4);
                Bs[g][r] = pack8(v0, v1);
            }
        }
        __syncthreads();
#pragma unroll
        for (int s = 0; s < 4; s++) {
            int g = s * 2 + (l >> 5);
            bf16x8 a0 = As[g][wm * 64 + (l & 31)];
            bf16x8 a1 = As[g][wm * 64 + 32 + (l & 31)];
            bf16x8 b0 = Bs[g][wn * 64 + (l & 31)];
            bf16x8 b1 = Bs[g][wn * 64 + 32 + (l & 31)];
            acc00 = __builtin_amdgcn_mfma_f32_32x32x16_bf16(a0, b0, acc00, 0, 0, 0);
            acc01 = __builtin_amdgcn_mfma_f32_32x32x16_bf16(a0, b1, acc01, 0, 0, 0);
            acc10 = __builtin_amdgcn_mfma_f32_32x32x16_bf16(a1, b0, acc10, 0, 0, 0);
            acc11 = __builtin_amdgcn_mfma_f32_32x32x16_bf16(a1, b1, acc11, 0, 0, 0);
        }
        __syncthreads();
    }

    int coll0 = wn * 64 + (l & 31);
    int coll1 = coll0 + 32;
    float yn0 = yn[nb * 128 + coll0], yn1 = yn[nb * 128 + coll1];
#pragma unroll
    for (int i = 0; i < 2; i++) {
#pragma unroll
        for (int p = 0; p < 16; p++) {
            float a0v = (i == 0) ? acc00[p] : acc10[p];
            float a1v = (i == 0) ? acc01[p] : acc11[p];
            int rl = i * 32 + (p & 3) + 8 * (p >> 2) + 4 * (l >> 5);
            float xr = xn[rb * 128 + wm * 64 + rl];
            float d0 = fmaxf(xr - 2.f * a0v + yn0, 0.f);
            float d1 = fmaxf(xr - 2.f * a1v + yn1, 0.f);
            unsigned k0 = (__float_as_uint(d0) & 0xFFFFFF00u) | (unsigned)coll0;
            unsigned k1 = (__float_as_uint(d1) & 0xFFFFFF00u) | (unsigned)coll1;
            unsigned best = k0 < k1 ? k0 : k1;
#pragma unroll
            for (int m = 1; m < 32; m <<= 1) {
                unsigned o2 = __shfl_xor(best, m);
                if (o2 < best) best = o2;
            }
            if ((l & 31) == 0) atomicMin(&rowbest[wm * 64 + rl], best);
        }
    }
    __syncthreads();
    if (t < 128) partials[(size_t)nb * GM + rb * 128 + t] = rowbest[t];
}

// ---------------- K6: expand u32 keys -> u64 global, min over 64 nb ----------------
__global__ void k_reduce1(const unsigned* __restrict__ partials,
                          unsigned long long* __restrict__ partial2) {
    int row = blockIdx.x * 256 + threadIdx.x;
    int ng = blockIdx.y;
    unsigned long long m = ~0ull;
    for (int n = 0; n < 64; n++) {
        int nb = ng * 64 + n;
        unsigned k = partials[(size_t)nb * GM + row];
        unsigned long long v = ((unsigned long long)(k & 0xFFFFFF00u) << 32)
                             | (unsigned)(nb * 128 + (k & 0xFFu));
        if (v < m) m = v;
    }
    partial2[ng * GM + row] = m;
}

// ---------------- K7: final min + scores + per-batch top-4 candidates ----------------
__global__ void k_reduce2cand(const unsigned long long* __restrict__ partial2,
                              float* __restrict__ scores, int* __restrict__ locs,
                              int* __restrict__ cand) {
    __shared__ unsigned long long key[256];
    __shared__ unsigned long long red[256];
    int b = blockIdx.x, t = threadIdx.x;
    int row = b * 256 + t;
    unsigned long long m = ~0ull;
    for (int g = 0; g < 8; g++) {
        unsigned long long v = partial2[g * GM + row];
        if (v < m) m = v;
    }
    float sc = sqrtf(__uint_as_float((unsigned)(m >> 32)));
    scores[row] = sc;
    locs[row] = (int)(m & 0xffffffffu);
    key[t] = ((unsigned long long)__float_as_uint(sc) << 32) | (unsigned)(255 - t);
    __syncthreads();
    for (int k = 0; k < 4; k++) {
        red[t] = key[t];
        __syncthreads();
        for (int s = 128; s; s >>= 1) {
            if (t < s && red[t + s] > red[t]) red[t] = red[t + s];
            __syncthreads();
        }
        unsigned long long win = red[0];
        int patch = 255 - (int)(win & 0xffffffffu);
        if (t == 0) cand[b * 4 + k] = b * SS + patch;
        __syncthreads();
        if (t == patch) key[t] = 0;
        __syncthreads();
    }
}

// ---------------- K9: exact fp32 re-search for 32 candidate rows ----------------
#define RF_ROWS 8
__global__ __launch_bounds__(256) void k_refine(
        const float* __restrict__ emb, const float* __restrict__ mb,
        const float* __restrict__ xn, const float* __restrict__ yn,
        const int* __restrict__ cand, unsigned long long* __restrict__ refpart) {
    __shared__ float cl[32 * CC];
    __shared__ float xnc[32];
    __shared__ int cr[32];
    __shared__ unsigned long long bmin[32];
    int t = threadIdx.x;
    if (t < 32) cr[t] = cand[t];
    __syncthreads();
    if (t < 32) { xnc[t] = xn[cr[t]]; bmin[t] = ~0ull; }
    for (int i = t; i < 32 * CC; i += 256) {
        int j = i / CC, p = i - j * CC;
        cl[i] = emb[(size_t)cr[j] * CC + p];
    }
    __syncthreads();
    int w = t >> 6, l = t & 63;
    int m0 = blockIdx.x * RF_ROWS + w * 2, m1 = m0 + 1;
    float2 r0[3], r1[3];
#pragma unroll
    for (int c = 0; c < 3; c++) {
        r0[c] = *(const float2*)&mb[(size_t)m0 * CC + c * 128 + l * 2];
        r1[c] = *(const float2*)&mb[(size_t)m1 * CC + c * 128 + l * 2];
    }
    float ya = yn[m0], yb = yn[m1];
    for (int j = 0; j < 32; j++) {
        float s0 = 0.f, s1 = 0.f;
#pragma unroll
        for (int c = 0; c < 3; c++) {
            float2 cv = *(const float2*)&cl[j * CC + c * 128 + l * 2];
            s0 = fmaf(r0[c].x, cv.x, s0); s0 = fmaf(r0[c].y, cv.y, s0);
            s1 = fmaf(r1[c].x, cv.x, s1); s1 = fmaf(r1[c].y, cv.y, s1);
        }
#pragma unroll
        for (int mm = 32; mm; mm >>= 1) { s0 += __shfl_xor(s0, mm); s1 += __shfl_xor(s1, mm); }
        if (l == 0) {
            float d0 = fmaxf(xnc[j] - 2.f * s0 + ya, 0.f);
            float d1 = fmaxf(xnc[j] - 2.f * s1 + yb, 0.f);
            unsigned long long k0 = ((unsigned long long)__float_as_uint(d0) << 32) | (unsigned)m0;
            unsigned long long k1 = ((unsigned long long)__float_as_uint(d1) << 32) | (unsigned)m1;
            unsigned long long kb = k0 < k1 ? k0 : k1;
            atomicMin(&bmin[j], kb);
        }
    }
    __syncthreads();
    if (t < 32) refpart[(size_t)blockIdx.x * 32 + t] = bmin[t];
}

__global__ void k_refred(const unsigned long long* __restrict__ refpart,
                         unsigned long long* __restrict__ keys2) {
    __shared__ unsigned long long red[256];
    int j = blockIdx.x, t = threadIdx.x;
    unsigned long long m = ~0ull;
    for (int i = t; i < MM / RF_ROWS; i += 256) {
        unsigned long long v = refpart[(size_t)i * 32 + j];
        if (v < m) m = v;
    }
    red[t] = m;
    __syncthreads();
    for (int s = 128; s; s >>= 1) {
        if (t < s && red[t + s] < red[t]) red[t] = red[t + s];
        __syncthreads();
    }
    if (t == 0) keys2[j] = red[0];
}

__global__ void k_final(const unsigned long long* __restrict__ keys2, const int* __restrict__ cand,
                        int* __restrict__ mp, float* __restrict__ scb, int* __restrict__ nn) {
    int b = threadIdx.x;
    if (b < BB) {
        float bestsc = -1.f;
        int bestpatch = 1 << 20, bestnn = 0;
        for (int k = 0; k < 4; k++) {
            unsigned long long key = keys2[b * 4 + k];
            float sc = sqrtf(__uint_as_float((unsigned)(key >> 32)));
            int patch = cand[b * 4 + k] & 255;
            int nnidx = (int)(key & 0xffffffffu);
            if (sc > bestsc || (sc == bestsc && patch < bestpatch)) {
                bestsc = sc; bestpatch = patch; bestnn = nnidx;
            }
        }
        mp[b] = bestpatch; scb[b] = bestsc; nn[b] = bestnn;
    }
}

// ---------------- K12: d_nn ----------------
__global__ void k_dnn(const float* __restrict__ mb, const float* __restrict__ yn,
                      const int* __restrict__ nn, float* __restrict__ dnn) {
    __shared__ float nnf[BB][CC];
    int t = threadIdx.x;
    for (int i = t; i < BB * CC; i += 256) {
        int bb = i / CC, cc = i % CC;
        nnf[bb][cc] = mb[(size_t)nn[bb] * CC + cc];
    }
    __syncthreads();
    int w = t >> 6, l = t & 63;
    int m = blockIdx.x * 4 + w;
    float accv[BB];
#pragma unroll
    for (int b = 0; b < BB; b++) accv[b] = 0.f;
    const float* r = mb + (size_t)m * CC;
#pragma unroll
    for (int i = 0; i < 6; i++) {
        float v = r[i * 64 + l];
#pragma unroll
        for (int b = 0; b < BB; b++) accv[b] = fmaf(v, nnf[b][i * 64 + l], accv[b]);
    }
#pragma unroll
    for (int b = 0; b < BB; b++) {
        float s = accv[b];
#pragma unroll
        for (int mm = 32; mm; mm >>= 1) s += __shfl_xor(s, mm);
        if (l == 0) {
            float d2 = fmaxf(yn[nn[b]] - 2.f * s + yn[m], 0.f);
            dnn[(size_t)b * MM + m] = sqrtf(d2);
        }
    }
}

// ---------------- K13a: per-chunk top-9 (64 chunks x 8 batches) ----------------
__global__ void k_top9a(const float* __restrict__ dnn, float* __restrict__ t9v,
                        int* __restrict__ t9i) {
    __shared__ float sd[256][TOPK];
    __shared__ int sx[256][TOPK];
    int c = blockIdx.x, b = blockIdx.y, t = threadIdx.x;
    float ld[TOPK];
    int li[TOPK];
#pragma unroll
    for (int k = 0; k < TOPK; k++) { ld[k] = INFINITY; li[k] = MM; }
    const float* d = dnn + (size_t)b * MM;
    for (int m = c * 1024 + t; m < (c + 1) * 1024; m += 256) {
        float v = d[m];
        if (v < ld[TOPK - 1] || (v == ld[TOPK - 1] && m < li[TOPK - 1])) {
            int k = TOPK - 1;
            while (k > 0 && (v < ld[k - 1] || (v == ld[k - 1] && m < li[k - 1]))) {
                ld[k] = ld[k - 1]; li[k] = li[k - 1]; k--;
            }
            ld[k] = v; li[k] = m;
        }
    }
    for (int k = 0; k < TOPK; k++) { sd[t][k] = ld[k]; sx[t][k] = li[k]; }
    __syncthreads();
    for (int s = 128; s; s >>= 1) {
        if (t < s) {
            float md[TOPK]; int mi[TOPK];
            int p = 0, q = 0;
            for (int k = 0; k < TOPK; k++) {
                float va = sd[t][p], vb = sd[t + s][q];
                int ia = sx[t][p], ib = sx[t + s][q];
                bool ta = (va < vb) || (va == vb && ia < ib);
                if (ta) { md[k] = va; mi[k] = ia; p++; }
                else    { md[k] = vb; mi[k] = ib; q++; }
            }
            for (int k = 0; k < TOPK; k++) { sd[t][k] = md[k]; sx[t][k] = mi[k]; }
        }
        __syncthreads();
    }
    if (t < TOPK) {
        t9v[(b * 64 + c) * TOPK + t] = sd[0][t];
        t9i[(b * 64 + c) * TOPK + t] = sx[0][t];
    }
}

// ---------------- K13b: merge 64 partial top-9s -> sup ----------------
__global__ void k_top9b(const float* __restrict__ t9v, const int* __restrict__ t9i,
                        int* __restrict__ sup) {
    __shared__ float sd[256][TOPK];
    __shared__ int sx[256][TOPK];
    int b = blockIdx.x, t = threadIdx.x;
    float ld[TOPK];
    int li[TOPK];
#pragma unroll
    for (int k = 0; k < TOPK; k++) { ld[k] = INFINITY; li[k] = MM; }
    for (int i = t; i < 64 * TOPK; i += 256) {
        float v = t9v[b * 64 * TOPK + i];
        int m = t9i[b * 64 * TOPK + i];
        if (v < ld[TOPK - 1] || (v == ld[TOPK - 1] && m < li[TOPK - 1])) {
            int k = TOPK - 1;
            while (k > 0 && (v < ld[k - 1] || (v == ld[k - 1] && m < li[k - 1]))) {
                ld[k] = ld[k - 1]; li[k] = li[k - 1]; k--;
            }
            ld[k] = v; li[k] = m;
        }
    }
    for (int k = 0; k < TOPK; k++) { sd[t][k] = ld[k]; sx[t][k] = li[k]; }
    __syncthreads();
    for (int s = 128; s; s >>= 1) {
        if (t < s) {
            float md[TOPK]; int mi[TOPK];
            int p = 0, q = 0;
            for (int k = 0; k < TOPK; k++) {
                float va = sd[t][p], vb = sd[t + s][q];
                int ia = sx[t][p], ib = sx[t + s][q];
                bool ta = (va < vb) || (va == vb && ia < ib);
                if (ta) { md[k] = va; mi[k] = ia; p++; }
                else    { md[k] = vb; mi[k] = ib; q++; }
            }
            for (int k = 0; k < TOPK; k++) { sd[t][k] = md[k]; sx[t][k] = mi[k]; }
        }
        __syncthreads();
    }
    if (t < TOPK) sup[b * TOPK + t] = sx[0][t];
}

// ---------------- K14: pred_score ----------------
__global__ void k_pred(const float* __restrict__ emb, const float* __restrict__ mb,
                       const float* __restrict__ yn, const float* __restrict__ xn,
                       const int* __restrict__ mp, const float* __restrict__ scb,
                       const int* __restrict__ sup, float* __restrict__ outp) {
    __shared__ float ds[TOPK];
    int b = blockIdx.x;
    int t = threadIdx.x;
    int w = t >> 6, l = t & 63;
    int mpb = mp[b];
    const float* mf = emb + ((size_t)b * SS + mpb) * CC;
    float xr = xn[b * SS + mpb];
    for (int k = w; k < TOPK; k += 4) {
        int sidx = sup[b * TOPK + k];
        const float* sr = mb + (size_t)sidx * CC;
        float s = 0.f;
#pragma unroll
        for (int i = 0; i < 6; i++) s = fmaf(mf[i * 64 + l], sr[i * 64 + l], s);
#pragma unroll
        for (int mm = 32; mm; mm >>= 1) s += __shfl_xor(s, mm);
        if (l == 0) ds[k] = sqrtf(fmaxf(xr - 2.f * s + yn[sidx], 0.f));
    }
    __syncthreads();
    if (t == 0) {
        float mx = ds[0];
        for (int k = 1; k < TOPK; k++) mx = fmaxf(mx, ds[k]);
        float num = expf(ds[0] - mx), den = 0.f;
        for (int k = 0; k < TOPK; k++) den += expf(ds[k] - mx);
        outp[b] = (1.f - num / den) * scb[b];
    }
}

// ---------------- K15: anomaly map scatter ----------------
__global__ void k_map(const float* __restrict__ scores, const int* __restrict__ labels,
                      float* __restrict__ out) {
    size_t i = (size_t)blockIdx.x * 256 + threadIdx.x;
    int b = (int)(i / HWP);
    out[i] = scores[b * SS + labels[i]];
}

extern "C" void kernel_launch(void* const* d_in, const int* in_sizes, int n_in,
                              void* d_out, int out_size, void* d_ws, size_t ws_size,
                              hipStream_t stream) {
    const float* feats  = (const float*)d_in[0];
    const int*   labels = (const int*)d_in[1];
    const float* mb     = (const float*)d_in[2];
    float* out = (float*)d_out;

    char* ws = (char*)d_ws;
    const size_t SZ_MBH   = (size_t)MM * CC * 2;              // 50.3 MB
    const size_t SZ_EMBH  = (size_t)GM * CC * 2;
    const size_t SZ_EMB   = (size_t)GM * CC * 4;
    const size_t SZ_YN    = (size_t)MM * 4;
    const size_t SZ_SMALL = 8192;
    const size_t SZ_P2    = (size_t)8 * GM * 8;
    const size_t SZ_T9    = (size_t)BB * 64 * TOPK * 4;       // 18.4 KB each
    const size_t SZ_KCP   = (size_t)NKC * BB * SS * CC * 4;   // 50.3 MB kc-partials
    const size_t SZ_BIG   = SZ_KCP;

    size_t need_full = SZ_MBH + SZ_EMBH + SZ_EMB + SZ_YN + 4 * SZ_SMALL + 2048
                     + SZ_P2 + 2 * SZ_T9 + SZ_BIG + 1024;
    bool lowmem = ws_size < need_full;

    size_t o = 0;
    unsigned short* mbh = nullptr;
    if (!lowmem) { mbh = (unsigned short*)(ws + o); o += SZ_MBH; }
    unsigned short* embh = (unsigned short*)(ws + o); o += SZ_EMBH;
    float* emb = (float*)(ws + o);                    o += SZ_EMB;
    float* yn  = (float*)(ws + o);                    o += SZ_YN;
    float* xn  = (float*)(ws + o);                    o += SZ_SMALL;
    unsigned* cntU = (unsigned*)(ws + o);             o += SZ_SMALL;
    float* scores = (float*)(ws + o);                 o += SZ_SMALL;
    int*   locs   = (int*)(ws + o);                   o += SZ_SMALL;
    int*   cand   = (int*)(ws + o);                   o += 256;
    unsigned long long* keys2 = (unsigned long long*)(ws + o); o += 256;
    int*   mp  = (int*)(ws + o);                      o += 128;
    float* scb = (float*)(ws + o);                    o += 128;
    int*   nn  = (int*)(ws + o);                      o += 128;
    int*   sup = (int*)(ws + o);                      o += 512;
    o = (o + 255) & ~(size_t)255;
    float* t9v = (float*)(ws + o);                    o += SZ_T9;
    int*   t9i = (int*)(ws + o);                      o += SZ_T9;
    o = (o + 255) & ~(size_t)255;
    unsigned long long* partial2 = (unsigned long long*)(ws + o); o += SZ_P2;
    char* big = ws + o;
    float* kcpart = (float*)big;                                   // segsum partials
    unsigned* partials = (unsigned*)big;                           // gemm u32 partials (after kcpart dead)
    unsigned long long* refpart  = (unsigned long long*)big;       // after partials consumed
    float* dnn = (float*)(big + 4194304);                          // disjoint from refpart (2 MB)

    hipMemsetAsync(cntU, 0, (size_t)GM * 4, stream);
    k_counts2<<<dim3(49, BB), 256, 0, stream>>>(labels, cntU);

    if (!lowmem) {
        k_segsum6<false><<<dim3(NKC, 6, BB), 256, 0, stream>>>(feats, labels, kcpart);
        k_cvtmb<<<MM / 4, 256, 0, stream>>>(mb, mbh, yn);
        k_embfin2<<<GM, 64, 0, stream>>>(kcpart, cntU, emb, xn, embh);
        k_gemm<false><<<8192, 256, 0, stream>>>(embh, mbh, mb, xn, yn, partials);
    } else {
        hipMemsetAsync(emb, 0, SZ_EMB, stream);
        k_segsum6<true><<<dim3(NKC, 6, BB), 256, 0, stream>>>(feats, labels, emb);
        k_ynorm<<<MM / 4, 256, 0, stream>>>(mb, yn);
        k_embfin<<<GM, 64, 0, stream>>>(emb, cntU, xn, embh);
        k_gemm<true><<<8192, 256, 0, stream>>>(embh, embh, mb, xn, yn, partials);
    }

    k_reduce1<<<dim3(8, 8), 256, 0, stream>>>(partials, partial2);
    k_reduce2cand<<<BB, 256, 0, stream>>>(partial2, scores, locs, cand);
    k_refine<<<MM / RF_ROWS, 256, 0, stream>>>(emb, mb, xn, yn, cand, refpart);
    k_refred<<<32, 256, 0, stream>>>(refpart, keys2);
    k_final<<<1, 64, 0, stream>>>(keys2, cand, mp, scb, nn);
    k_dnn<<<MM / 4, 256, 0, stream>>>(mb, yn, nn, dnn);
    k_top9a<<<dim3(64, BB), 256, 0, stream>>>(dnn, t9v, t9i);
    k_top9b<<<BB, 256, 0, stream>>>(t9v, t9i, sup);
    k_pred<<<BB, 256, 0, stream>>>(emb, mb, yn, xn, mp, scb, sup, out + (size_t)BB * HWP);
    k_map<<<(BB * HWP) / 256, 256, 0, stream>>>(scores, labels, out);
}

// Round 9
// 766.235 us; speedup vs baseline: 1.5304x; 1.1205x over previous
//
#include <hip/hip_runtime.h>

#define BB 8
#define CC 384
#define HWP 50176
#define SS 256
#define MM 65536
#define TOPK 9
#define GM 2048          // BB*SS emb rows
#define NKC 16           // K-split blocks for segsum

typedef __attribute__((ext_vector_type(8))) __bf16 bf16x8;
typedef __attribute__((ext_vector_type(16))) float fx16;
typedef __attribute__((ext_vector_type(4))) float f32x4;

__device__ __forceinline__ unsigned short f2bf_rne(float x) {
    unsigned u = __float_as_uint(x);
    unsigned r = (u + 0x7FFFu + ((u >> 16) & 1u)) >> 16;
    return (unsigned short)r;
}

__device__ __forceinline__ bf16x8 pack8(float4 v0, float4 v1) {
    bf16x8 r;
    r[0] = (__bf16)v0.x; r[1] = (__bf16)v0.y; r[2] = (__bf16)v0.z; r[3] = (__bf16)v0.w;
    r[4] = (__bf16)v1.x; r[5] = (__bf16)v1.y; r[6] = (__bf16)v1.z; r[7] = (__bf16)v1.w;
    return r;
}

__device__ __forceinline__ void gl_lds16(const void* g, void* l) {
    auto gp = (const __attribute__((address_space(1))) unsigned int*)g;
    auto lp = (__attribute__((address_space(3))) unsigned int*)l;
    __builtin_amdgcn_global_load_lds(gp, lp, 16, 0, 0);
}

// ---------------- K1: per-batch label counts (parallel) ----------------
__global__ void k_counts2(const int* __restrict__ labels, unsigned* __restrict__ cntU) {
    __shared__ unsigned cnt[SS];
    int kc = blockIdx.x, b = blockIdx.y;   // (49, 8)
    int t = threadIdx.x;
    cnt[t] = 0u;
    __syncthreads();
    int4 lv = ((const int4*)(labels + (size_t)b * HWP + kc * 1024))[t];
    atomicAdd(&cnt[lv.x], 1u);
    atomicAdd(&cnt[lv.y], 1u);
    atomicAdd(&cnt[lv.z], 1u);
    atomicAdd(&cnt[lv.w], 1u);
    __syncthreads();
    if (cnt[t]) atomicAdd(&cntU[b * SS + t], cnt[t]);
}

// ---------------- K2: segment sums as MFMA GEMM v7 ----------------
// C[c][s] = sum_k feats[c][k] * onehot[k][s].  A = feats (dense, LDS-staged),
// B = one-hot built in registers; wave w owns s-range [w*64, w*64+64) so the
// 4 waves' one-hot builds are disjoint (4x less VALU than v6's shared-A form).
// grid (kc=NKC, cg=6, b=8); block 256.
template <bool ATOMIC>
__global__ __launch_bounds__(256) void k_segsum7(const float* __restrict__ feats,
                                                 const int* __restrict__ labels,
                                                 float* __restrict__ outp) {
    __shared__ bf16x8 Fs[8][64];    // Fs[g][c] = feats[c][k0+g*8 .. +7], 8 KB
    __shared__ int labL[64];
    int kc = blockIdx.x, cg = blockIdx.y, b = blockIdx.z;
    int t = threadIdx.x, l = t & 63, w = t >> 6;
    int c0b = cg * 64;
    int g16 = l >> 4;        // 0..3
    int rowl = l & 15;

    f32x4 acc[4][4];         // [rt(channel-tile)][st(s-tile)]
#pragma unroll
    for (int i = 0; i < 4; i++)
#pragma unroll
        for (int j = 0; j < 4; j++) acc[i][j] = (f32x4){0.f, 0.f, 0.f, 0.f};

    const float* fb = feats + ((size_t)b * CC + c0b) * HWP;
    const int* lbase = labels + (size_t)b * HWP + kc * 3136;

    // per-thread staging slots: ids 2t,2t+1 -> same channel row, 16 consecutive floats
    int id0 = t * 2;
    int cl = id0 >> 3, g0 = id0 & 7;
    const float* tbase = fb + (size_t)cl * HWP + kc * 3136 + g0 * 8;

    // prologue: prefetch tile 0
    float4 ra0 = *(const float4*)(tbase + 0);
    float4 ra1 = *(const float4*)(tbase + 4);
    float4 rb0 = *(const float4*)(tbase + 8);
    float4 rb1 = *(const float4*)(tbase + 12);
    int4 rl4 = (t < 16) ? ((const int4*)lbase)[t] : (int4){0, 0, 0, 0};

    for (int tt = 0; tt < 49; tt++) {
        __syncthreads();   // prev compute done; Fs/labL free
        if (t < 16) ((int4*)labL)[t] = rl4;
        Fs[g0][cl] = pack8(ra0, ra1);
        Fs[g0 + 1][cl] = pack8(rb0, rb1);
        if (tt + 1 < 49) {
            const float* nb_ = tbase + (size_t)(tt + 1) * 64;
            ra0 = *(const float4*)(nb_ + 0);
            ra1 = *(const float4*)(nb_ + 4);
            rb0 = *(const float4*)(nb_ + 8);
            rb1 = *(const float4*)(nb_ + 12);
            if (t < 16) rl4 = ((const int4*)(lbase + (tt + 1) * 64))[t];
        }
        __syncthreads();   // Fs/labL ready

        // A-feat fragments: af[ks][rt], element e = feats[rt*16+rowl][ks*32+g16*8+e]
        bf16x8 af0[4], af1[4];
#pragma unroll
        for (int rt = 0; rt < 4; rt++) {
            af0[rt] = Fs[g16][rt * 16 + rowl];
            af1[rt] = Fs[4 + g16][rt * 16 + rowl];
        }
        // per-lane labels for this lane's k-slots (broadcast reads, conflict-free)
        int4 lo0 = ((int4*)labL)[g16 * 2 + 0];
        int4 hi0 = ((int4*)labL)[g16 * 2 + 1];
        int4 lo1 = ((int4*)labL)[8 + g16 * 2 + 0];
        int4 hi1 = ((int4*)labL)[8 + g16 * 2 + 1];

#pragma unroll
        for (int st = 0; st < 4; st++) {
            int tgt = w * 64 + st * 16 + rowl;   // this lane's s-column
            union { unsigned u[4]; bf16x8 v; } B;
            // ks = 0
            B.u[0] = (lo0.x == tgt ? 0x3F80u : 0u) | (lo0.y == tgt ? 0x3F800000u : 0u);
            B.u[1] = (lo0.z == tgt ? 0x3F80u : 0u) | (lo0.w == tgt ? 0x3F800000u : 0u);
            B.u[2] = (hi0.x == tgt ? 0x3F80u : 0u) | (hi0.y == tgt ? 0x3F800000u : 0u);
            B.u[3] = (hi0.z == tgt ? 0x3F80u : 0u) | (hi0.w == tgt ? 0x3F800000u : 0u);
#pragma unroll
            for (int rt = 0; rt < 4; rt++)
                acc[rt][st] = __builtin_amdgcn_mfma_f32_16x16x32_bf16(af0[rt], B.v, acc[rt][st], 0, 0, 0);
            // ks = 1
            B.u[0] = (lo1.x == tgt ? 0x3F80u : 0u) | (lo1.y == tgt ? 0x3F800000u : 0u);
            B.u[1] = (lo1.z == tgt ? 0x3F80u : 0u) | (lo1.w == tgt ? 0x3F800000u : 0u);
            B.u[2] = (hi1.x == tgt ? 0x3F80u : 0u) | (hi1.y == tgt ? 0x3F800000u : 0u);
            B.u[3] = (hi1.z == tgt ? 0x3F80u : 0u) | (hi1.w == tgt ? 0x3F800000u : 0u);
#pragma unroll
            for (int rt = 0; rt < 4; rt++)
                acc[rt][st] = __builtin_amdgcn_mfma_f32_16x16x32_bf16(af1[rt], B.v, acc[rt][st], 0, 0, 0);
        }
    }

    // flush: C col = s = w*64 + st*16 + rowl; row = c = c0b + rt*16 + g16*4 + r
    if (ATOMIC) {
#pragma unroll
        for (int rt = 0; rt < 4; rt++)
#pragma unroll
            for (int st = 0; st < 4; st++)
#pragma unroll
                for (int r = 0; r < 4; r++) {
                    int s = w * 64 + st * 16 + rowl;
                    int c = c0b + rt * 16 + g16 * 4 + r;
                    atomicAdd(&outp[((size_t)b * SS + s) * CC + c], acc[rt][st][r]);
                }
    } else {
        float* dst = outp + (size_t)(kc * BB + b) * SS * CC;
#pragma unroll
        for (int rt = 0; rt < 4; rt++)
#pragma unroll
            for (int st = 0; st < 4; st++)
#pragma unroll
                for (int r = 0; r < 4; r++) {
                    int s = w * 64 + st * 16 + rowl;
                    int c = c0b + rt * 16 + g16 * 4 + r;
                    dst[(size_t)s * CC + c] = acc[rt][st][r];
                }
    }
}

// ---------------- K3: bank fp32->bf16 + row norms ----------------
__global__ void k_cvtmb(const float* __restrict__ mb, unsigned short* __restrict__ mbh,
                        float* __restrict__ yn) {
    int w = threadIdx.x >> 6, l = threadIdx.x & 63;
    int row = blockIdx.x * 4 + w;
    const float* r = mb + (size_t)row * CC;
    unsigned short* o = mbh + (size_t)row * CC;
    float s = 0.f;
#pragma unroll
    for (int i = 0; i < 6; i++) {
        float v = r[i * 64 + l];
        s = fmaf(v, v, s);
        o[i * 64 + l] = f2bf_rne(v);
    }
#pragma unroll
    for (int m = 32; m; m >>= 1) s += __shfl_xor(s, m);
    if (l == 0) yn[row] = s;
}

__global__ void k_ynorm(const float* __restrict__ mb, float* __restrict__ yn) {
    int w = threadIdx.x >> 6, l = threadIdx.x & 63;
    int row = blockIdx.x * 4 + w;
    const float* r = mb + (size_t)row * CC;
    float s = 0.f;
#pragma unroll
    for (int i = 0; i < 6; i++) { float v = r[i * 64 + l]; s = fmaf(v, v, s); }
#pragma unroll
    for (int m = 32; m; m >>= 1) s += __shfl_xor(s, m);
    if (l == 0) yn[row] = s;
}

// ---------------- K4a: reduce kc-partials -> emb + norms + bf16 copy ----------------
__global__ void k_embfin2(const float* __restrict__ kcpart, const unsigned* __restrict__ counts,
                          float* __restrict__ emb, float* __restrict__ xn,
                          unsigned short* __restrict__ embh) {
    int i = blockIdx.x;
    int b = i >> 8, s256 = i & 255;
    int l = threadIdx.x;
    float a6[6] = {0.f, 0.f, 0.f, 0.f, 0.f, 0.f};
    for (int kc = 0; kc < NKC; kc++) {
        const float* row = kcpart + ((size_t)(kc * BB + b) * SS + s256) * CC;
#pragma unroll
        for (int j = 0; j < 6; j++) a6[j] += row[j * 64 + l];
    }
    float inv = 1.f / fmaxf((float)counts[i], 1.f);
    float ss = 0.f;
#pragma unroll
    for (int j = 0; j < 6; j++) {
        float v = a6[j] * inv;
        emb[(size_t)i * CC + j * 64 + l] = v;
        embh[(size_t)i * CC + j * 64 + l] = f2bf_rne(v);
        ss = fmaf(v, v, ss);
    }
#pragma unroll
    for (int m = 32; m; m >>= 1) ss += __shfl_xor(ss, m);
    if (l == 0) xn[i] = ss;
}

// ---------------- K4b: finalize emb in place (lowmem path) ----------------
__global__ void k_embfin(float* __restrict__ emb, const unsigned* __restrict__ counts,
                         float* __restrict__ xn, unsigned short* __restrict__ embh) {
    int i = blockIdx.x, l = threadIdx.x;
    float inv = 1.f / fmaxf((float)counts[i], 1.f);
    float* e = emb + (size_t)i * CC;
    unsigned short* o = embh + (size_t)i * CC;
    float s = 0.f;
#pragma unroll
    for (int j = 0; j < 6; j++) {
        float v = e[j * 64 + l] * inv;
        e[j * 64 + l] = v;
        o[j * 64 + l] = f2bf_rne(v);
        s = fmaf(v, v, s);
    }
#pragma unroll
    for (int m = 32; m; m >>= 1) s += __shfl_xor(s, m);
    if (l == 0) xn[i] = s;
}

// ---------------- K5: 128x128 bf16 MFMA GEMM + fused row-min (u32 keys) ----------------
template <bool REGB>
__global__ __launch_bounds__(256) void k_gemm(
        const unsigned short* __restrict__ Ah, const unsigned short* __restrict__ Bh,
        const float* __restrict__ Bf,
        const float* __restrict__ xn, const float* __restrict__ yn,
        unsigned* __restrict__ partials) {
    __shared__ bf16x8 As[8][128];
    __shared__ bf16x8 Bs[8][128];
    __shared__ unsigned rowbest[128];
    int bid = blockIdx.x;
    int swz = (bid & 7) * 1024 + (bid >> 3);   // bijective: 8192 % 8 == 0
    int rb = swz & 15, nb = swz >> 4;
    int t = threadIdx.x;
    int w = t >> 6, l = t & 63;
    int wm = w & 1, wn = w >> 1;

    if (t < 128) rowbest[t] = 0xFFFFFFFFu;

    fx16 acc00, acc01, acc10, acc11;
#pragma unroll
    for (int p = 0; p < 16; p++) { acc00[p] = 0.f; acc01[p] = 0.f; acc10[p] = 0.f; acc11[p] = 0.f; }

    const unsigned short* Abase = Ah + (size_t)(rb * 128) * CC;
    const unsigned short* Bbase = REGB ? nullptr : (Bh + (size_t)(nb * 128) * CC);
    const float* Bfbase = Bf + (size_t)(nb * 128) * CC;

    for (int kt = 0; kt < 6; kt++) {
        int k0 = kt * 64;
#pragma unroll
        for (int q = 0; q < 4; q++) {
            int c = q * 256 + t;
            int r = c & 127, g = c >> 7;
            gl_lds16(Abase + (size_t)r * CC + k0 + g * 8, &As[g][r]);
            if (!REGB) {
                gl_lds16(Bbase + (size_t)r * CC + k0 + g * 8, &Bs[g][r]);
            } else {
                const float* src = Bfbase + (size_t)r * CC + k0 + g * 8;
                float4 v0 = *(const float4*)(src);
                float4 v1 = *(const float4*)(src + 4);
                Bs[g][r] = pack8(v0, v1);
            }
        }
        __syncthreads();
#pragma unroll
        for (int s = 0; s < 4; s++) {
            int g = s * 2 + (l >> 5);
            bf16x8 a0 = As[g][wm * 64 + (l & 31)];
            bf16x8 a1 = As[g][wm * 64 + 32 + (l & 31)];
            bf16x8 b0 = Bs[g][wn * 64 + (l & 31)];
            bf16x8 b1 = Bs[g][wn * 64 + 32 + (l & 31)];
            acc00 = __builtin_amdgcn_mfma_f32_32x32x16_bf16(a0, b0, acc00, 0, 0, 0);
            acc01 = __builtin_amdgcn_mfma_f32_32x32x16_bf16(a0, b1, acc01, 0, 0, 0);
            acc10 = __builtin_amdgcn_mfma_f32_32x32x16_bf16(a1, b0, acc10, 0, 0, 0);
            acc11 = __builtin_amdgcn_mfma_f32_32x32x16_bf16(a1, b1, acc11, 0, 0, 0);
        }
        __syncthreads();
    }

    int coll0 = wn * 64 + (l & 31);
    int coll1 = coll0 + 32;
    float yn0 = yn[nb * 128 + coll0], yn1 = yn[nb * 128 + coll1];
#pragma unroll
    for (int i = 0; i < 2; i++) {
#pragma unroll
        for (int p = 0; p < 16; p++) {
            float a0v = (i == 0) ? acc00[p] : acc10[p];
            float a1v = (i == 0) ? acc01[p] : acc11[p];
            int rl = i * 32 + (p & 3) + 8 * (p >> 2) + 4 * (l >> 5);
            float xr = xn[rb * 128 + wm * 64 + rl];
            float d0 = fmaxf(xr - 2.f * a0v + yn0, 0.f);
            float d1 = fmaxf(xr - 2.f * a1v + yn1, 0.f);
            unsigned k0 = (__float_as_uint(d0) & 0xFFFFFF00u) | (unsigned)coll0;
            unsigned k1 = (__float_as_uint(d1) & 0xFFFFFF00u) | (unsigned)coll1;
            unsigned best = k0 < k1 ? k0 : k1;
#pragma unroll
            for (int m = 1; m < 32; m <<= 1) {
                unsigned o2 = __shfl_xor(best, m);
                if (o2 < best) best = o2;
            }
            if ((l & 31) == 0) atomicMin(&rowbest[wm * 64 + rl], best);
        }
    }
    __syncthreads();
    if (t < 128) partials[(size_t)nb * GM + rb * 128 + t] = rowbest[t];
}

// ---------------- K6: expand u32 keys -> u64 global, min over 64 nb ----------------
__global__ void k_reduce1(const unsigned* __restrict__ partials,
                          unsigned long long* __restrict__ partial2) {
    int row = blockIdx.x * 256 + threadIdx.x;
    int ng = blockIdx.y;
    unsigned long long m = ~0ull;
    for (int n = 0; n < 64; n++) {
        int nb = ng * 64 + n;
        unsigned k = partials[(size_t)nb * GM + row];
        unsigned long long v = ((unsigned long long)(k & 0xFFFFFF00u) << 32)
                             | (unsigned)(nb * 128 + (k & 0xFFu));
        if (v < m) m = v;
    }
    partial2[ng * GM + row] = m;
}

// ---------------- K7: final min + scores + per-batch top-4 candidates ----------------
__global__ void k_reduce2cand(const unsigned long long* __restrict__ partial2,
                              float* __restrict__ scores, int* __restrict__ locs,
                              int* __restrict__ cand) {
    __shared__ unsigned long long key[256];
    __shared__ unsigned long long red[256];
    int b = blockIdx.x, t = threadIdx.x;
    int row = b * 256 + t;
    unsigned long long m = ~0ull;
    for (int g = 0; g < 8; g++) {
        unsigned long long v = partial2[g * GM + row];
        if (v < m) m = v;
    }
    float sc = sqrtf(__uint_as_float((unsigned)(m >> 32)));
    scores[row] = sc;
    locs[row] = (int)(m & 0xffffffffu);
    key[t] = ((unsigned long long)__float_as_uint(sc) << 32) | (unsigned)(255 - t);
    __syncthreads();
    for (int k = 0; k < 4; k++) {
        red[t] = key[t];
        __syncthreads();
        for (int s = 128; s; s >>= 1) {
            if (t < s && red[t + s] > red[t]) red[t] = red[t + s];
            __syncthreads();
        }
        unsigned long long win = red[0];
        int patch = 255 - (int)(win & 0xffffffffu);
        if (t == 0) cand[b * 4 + k] = b * SS + patch;
        __syncthreads();
        if (t == patch) key[t] = 0;
        __syncthreads();
    }
}

// ---------------- K9: exact fp32 re-search for 32 candidate rows ----------------
#define RF_ROWS 8
__global__ __launch_bounds__(256) void k_refine(
        const float* __restrict__ emb, const float* __restrict__ mb,
        const float* __restrict__ xn, const float* __restrict__ yn,
        const int* __restrict__ cand, unsigned long long* __restrict__ refpart) {
    __shared__ float cl[32 * CC];
    __shared__ float xnc[32];
    __shared__ int cr[32];
    __shared__ unsigned long long bmin[32];
    int t = threadIdx.x;
    if (t < 32) cr[t] = cand[t];
    __syncthreads();
    if (t < 32) { xnc[t] = xn[cr[t]]; bmin[t] = ~0ull; }
    for (int i = t; i < 32 * CC; i += 256) {
        int j = i / CC, p = i - j * CC;
        cl[i] = emb[(size_t)cr[j] * CC + p];
    }
    __syncthreads();
    int w = t >> 6, l = t & 63;
    int m0 = blockIdx.x * RF_ROWS + w * 2, m1 = m0 + 1;
    float2 r0[3], r1[3];
#pragma unroll
    for (int c = 0; c < 3; c++) {
        r0[c] = *(const float2*)&mb[(size_t)m0 * CC + c * 128 + l * 2];
        r1[c] = *(const float2*)&mb[(size_t)m1 * CC + c * 128 + l * 2];
    }
    float ya = yn[m0], yb = yn[m1];
    for (int j = 0; j < 32; j++) {
        float s0 = 0.f, s1 = 0.f;
#pragma unroll
        for (int c = 0; c < 3; c++) {
            float2 cv = *(const float2*)&cl[j * CC + c * 128 + l * 2];
            s0 = fmaf(r0[c].x, cv.x, s0); s0 = fmaf(r0[c].y, cv.y, s0);
            s1 = fmaf(r1[c].x, cv.x, s1); s1 = fmaf(r1[c].y, cv.y, s1);
        }
#pragma unroll
        for (int mm = 32; mm; mm >>= 1) { s0 += __shfl_xor(s0, mm); s1 += __shfl_xor(s1, mm); }
        if (l == 0) {
            float d0 = fmaxf(xnc[j] - 2.f * s0 + ya, 0.f);
            float d1 = fmaxf(xnc[j] - 2.f * s1 + yb, 0.f);
            unsigned long long k0 = ((unsigned long long)__float_as_uint(d0) << 32) | (unsigned)m0;
            unsigned long long k1 = ((unsigned long long)__float_as_uint(d1) << 32) | (unsigned)m1;
            unsigned long long kb = k0 < k1 ? k0 : k1;
            atomicMin(&bmin[j], kb);
        }
    }
    __syncthreads();
    if (t < 32) refpart[(size_t)blockIdx.x * 32 + t] = bmin[t];
}

__global__ void k_refred(const unsigned long long* __restrict__ refpart,
                         unsigned long long* __restrict__ keys2) {
    __shared__ unsigned long long red[256];
    int j = blockIdx.x, t = threadIdx.x;
    unsigned long long m = ~0ull;
    for (int i = t; i < MM / RF_ROWS; i += 256) {
        unsigned long long v = refpart[(size_t)i * 32 + j];
        if (v < m) m = v;
    }
    red[t] = m;
    __syncthreads();
    for (int s = 128; s; s >>= 1) {
        if (t < s && red[t + s] < red[t]) red[t] = red[t + s];
        __syncthreads();
    }
    if (t == 0) keys2[j] = red[0];
}

__global__ void k_final(const unsigned long long* __restrict__ keys2, const int* __restrict__ cand,
                        int* __restrict__ mp, float* __restrict__ scb, int* __restrict__ nn) {
    int b = threadIdx.x;
    if (b < BB) {
        float bestsc = -1.f;
        int bestpatch = 1 << 20, bestnn = 0;
        for (int k = 0; k < 4; k++) {
            unsigned long long key = keys2[b * 4 + k];
            float sc = sqrtf(__uint_as_float((unsigned)(key >> 32)));
            int patch = cand[b * 4 + k] & 255;
            int nnidx = (int)(key & 0xffffffffu);
            if (sc > bestsc || (sc == bestsc && patch < bestpatch)) {
                bestsc = sc; bestpatch = patch; bestnn = nnidx;
            }
        }
        mp[b] = bestpatch; scb[b] = bestsc; nn[b] = bestnn;
    }
}

// ---------------- K12: d_nn ----------------
__global__ void k_dnn(const float* __restrict__ mb, const float* __restrict__ yn,
                      const int* __restrict__ nn, float* __restrict__ dnn) {
    __shared__ float nnf[BB][CC];
    int t = threadIdx.x;
    for (int i = t; i < BB * CC; i += 256) {
        int bb = i / CC, cc = i % CC;
        nnf[bb][cc] = mb[(size_t)nn[bb] * CC + cc];
    }
    __syncthreads();
    int w = t >> 6, l = t & 63;
    int m = blockIdx.x * 4 + w;
    float accv[BB];
#pragma unroll
    for (int b = 0; b < BB; b++) accv[b] = 0.f;
    const float* r = mb + (size_t)m * CC;
#pragma unroll
    for (int i = 0; i < 6; i++) {
        float v = r[i * 64 + l];
#pragma unroll
        for (int b = 0; b < BB; b++) accv[b] = fmaf(v, nnf[b][i * 64 + l], accv[b]);
    }
#pragma unroll
    for (int b = 0; b < BB; b++) {
        float s = accv[b];
#pragma unroll
        for (int mm = 32; mm; mm >>= 1) s += __shfl_xor(s, mm);
        if (l == 0) {
            float d2 = fmaxf(yn[nn[b]] - 2.f * s + yn[m], 0.f);
            dnn[(size_t)b * MM + m] = sqrtf(d2);
        }
    }
}

// ---------------- K13a: per-chunk top-9 (64 chunks x 8 batches) ----------------
__global__ void k_top9a(const float* __restrict__ dnn, float* __restrict__ t9v,
                        int* __restrict__ t9i) {
    __shared__ float sd[256][TOPK];
    __shared__ int sx[256][TOPK];
    int c = blockIdx.x, b = blockIdx.y, t = threadIdx.x;
    float ld[TOPK];
    int li[TOPK];
#pragma unroll
    for (int k = 0; k < TOPK; k++) { ld[k] = INFINITY; li[k] = MM; }
    const float* d = dnn + (size_t)b * MM;
    for (int m = c * 1024 + t; m < (c + 1) * 1024; m += 256) {
        float v = d[m];
        if (v < ld[TOPK - 1] || (v == ld[TOPK - 1] && m < li[TOPK - 1])) {
            int k = TOPK - 1;
            while (k > 0 && (v < ld[k - 1] || (v == ld[k - 1] && m < li[k - 1]))) {
                ld[k] = ld[k - 1]; li[k] = li[k - 1]; k--;
            }
            ld[k] = v; li[k] = m;
        }
    }
    for (int k = 0; k < TOPK; k++) { sd[t][k] = ld[k]; sx[t][k] = li[k]; }
    __syncthreads();
    for (int s = 128; s; s >>= 1) {
        if (t < s) {
            float md[TOPK]; int mi[TOPK];
            int p = 0, q = 0;
            for (int k = 0; k < TOPK; k++) {
                float va = sd[t][p], vb = sd[t + s][q];
                int ia = sx[t][p], ib = sx[t + s][q];
                bool ta = (va < vb) || (va == vb && ia < ib);
                if (ta) { md[k] = va; mi[k] = ia; p++; }
                else    { md[k] = vb; mi[k] = ib; q++; }
            }
            for (int k = 0; k < TOPK; k++) { sd[t][k] = md[k]; sx[t][k] = mi[k]; }
        }
        __syncthreads();
    }
    if (t < TOPK) {
        t9v[(b * 64 + c) * TOPK + t] = sd[0][t];
        t9i[(b * 64 + c) * TOPK + t] = sx[0][t];
    }
}

// ---------------- K13b: merge 64 partial top-9s -> sup ----------------
__global__ void k_top9b(const float* __restrict__ t9v, const int* __restrict__ t9i,
                        int* __restrict__ sup) {
    __shared__ float sd[256][TOPK];
    __shared__ int sx[256][TOPK];
    int b = blockIdx.x, t = threadIdx.x;
    float ld[TOPK];
    int li[TOPK];
#pragma unroll
    for (int k = 0; k < TOPK; k++) { ld[k] = INFINITY; li[k] = MM; }
    for (int i = t; i < 64 * TOPK; i += 256) {
        float v = t9v[b * 64 * TOPK + i];
        int m = t9i[b * 64 * TOPK + i];
        if (v < ld[TOPK - 1] || (v == ld[TOPK - 1] && m < li[TOPK - 1])) {
            int k = TOPK - 1;
            while (k > 0 && (v < ld[k - 1] || (v == ld[k - 1] && m < li[k - 1]))) {
                ld[k] = ld[k - 1]; li[k] = li[k - 1]; k--;
            }
            ld[k] = v; li[k] = m;
        }
    }
    for (int k = 0; k < TOPK; k++) { sd[t][k] = ld[k]; sx[t][k] = li[k]; }
    __syncthreads();
    for (int s = 128; s; s >>= 1) {
        if (t < s) {
            float md[TOPK]; int mi[TOPK];
            int p = 0, q = 0;
            for (int k = 0; k < TOPK; k++) {
                float va = sd[t][p], vb = sd[t + s][q];
                int ia = sx[t][p], ib = sx[t + s][q];
                bool ta = (va < vb) || (va == vb && ia < ib);
                if (ta) { md[k] = va; mi[k] = ia; p++; }
                else    { md[k] = vb; mi[k] = ib; q++; }
            }
            for (int k = 0; k < TOPK; k++) { sd[t][k] = md[k]; sx[t][k] = mi[k]; }
        }
        __syncthreads();
    }
    if (t < TOPK) sup[b * TOPK + t] = sx[0][t];
}

// ---------------- K14: pred_score ----------------
__global__ void k_pred(const float* __restrict__ emb, const float* __restrict__ mb,
                       const float* __restrict__ yn, const float* __restrict__ xn,
                       const int* __restrict__ mp, const float* __restrict__ scb,
                       const int* __restrict__ sup, float* __restrict__ outp) {
    __shared__ float ds[TOPK];
    int b = blockIdx.x;
    int t = threadIdx.x;
    int w = t >> 6, l = t & 63;
    int mpb = mp[b];
    const float* mf = emb + ((size_t)b * SS + mpb) * CC;
    float xr = xn[b * SS + mpb];
    for (int k = w; k < TOPK; k += 4) {
        int sidx = sup[b * TOPK + k];
        const float* sr = mb + (size_t)sidx * CC;
        float s = 0.f;
#pragma unroll
        for (int i = 0; i < 6; i++) s = fmaf(mf[i * 64 + l], sr[i * 64 + l], s);
#pragma unroll
        for (int mm = 32; mm; mm >>= 1) s += __shfl_xor(s, mm);
        if (l == 0) ds[k] = sqrtf(fmaxf(xr - 2.f * s + yn[sidx], 0.f));
    }
    __syncthreads();
    if (t == 0) {
        float mx = ds[0];
        for (int k = 1; k < TOPK; k++) mx = fmaxf(mx, ds[k]);
        float num = expf(ds[0] - mx), den = 0.f;
        for (int k = 0; k < TOPK; k++) den += expf(ds[k] - mx);
        outp[b] = (1.f - num / den) * scb[b];
    }
}

// ---------------- K15: anomaly map scatter ----------------
__global__ void k_map(const float* __restrict__ scores, const int* __restrict__ labels,
                      float* __restrict__ out) {
    size_t i = (size_t)blockIdx.x * 256 + threadIdx.x;
    int b = (int)(i / HWP);
    out[i] = scores[b * SS + labels[i]];
}

extern "C" void kernel_launch(void* const* d_in, const int* in_sizes, int n_in,
                              void* d_out, int out_size, void* d_ws, size_t ws_size,
                              hipStream_t stream) {
    const float* feats  = (const float*)d_in[0];
    const int*   labels = (const int*)d_in[1];
    const float* mb     = (const float*)d_in[2];
    float* out = (float*)d_out;

    char* ws = (char*)d_ws;
    const size_t SZ_MBH   = (size_t)MM * CC * 2;              // 50.3 MB
    const size_t SZ_EMBH  = (size_t)GM * CC * 2;
    const size_t SZ_EMB   = (size_t)GM * CC * 4;
    const size_t SZ_YN    = (size_t)MM * 4;
    const size_t SZ_SMALL = 8192;
    const size_t SZ_P2    = (size_t)8 * GM * 8;
    const size_t SZ_T9    = (size_t)BB * 64 * TOPK * 4;       // 18.4 KB each
    const size_t SZ_KCP   = (size_t)NKC * BB * SS * CC * 4;   // 50.3 MB kc-partials
    const size_t SZ_BIG   = SZ_KCP;

    size_t need_full = SZ_MBH + SZ_EMBH + SZ_EMB + SZ_YN + 4 * SZ_SMALL + 2048
                     + SZ_P2 + 2 * SZ_T9 + SZ_BIG + 1024;
    bool lowmem = ws_size < need_full;

    size_t o = 0;
    unsigned short* mbh = nullptr;
    if (!lowmem) { mbh = (unsigned short*)(ws + o); o += SZ_MBH; }
    unsigned short* embh = (unsigned short*)(ws + o); o += SZ_EMBH;
    float* emb = (float*)(ws + o);                    o += SZ_EMB;
    float* yn  = (float*)(ws + o);                    o += SZ_YN;
    float* xn  = (float*)(ws + o);                    o += SZ_SMALL;
    unsigned* cntU = (unsigned*)(ws + o);             o += SZ_SMALL;
    float* scores = (float*)(ws + o);                 o += SZ_SMALL;
    int*   locs   = (int*)(ws + o);                   o += SZ_SMALL;
    int*   cand   = (int*)(ws + o);                   o += 256;
    unsigned long long* keys2 = (unsigned long long*)(ws + o); o += 256;
    int*   mp  = (int*)(ws + o);                      o += 128;
    float* scb = (float*)(ws + o);                    o += 128;
    int*   nn  = (int*)(ws + o);                      o += 128;
    int*   sup = (int*)(ws + o);                      o += 512;
    o = (o + 255) & ~(size_t)255;
    float* t9v = (float*)(ws + o);                    o += SZ_T9;
    int*   t9i = (int*)(ws + o);                      o += SZ_T9;
    o = (o + 255) & ~(size_t)255;
    unsigned long long* partial2 = (unsigned long long*)(ws + o); o += SZ_P2;
    char* big = ws + o;
    float* kcpart = (float*)big;                                   // segsum partials
    unsigned* partials = (unsigned*)big;                           // gemm u32 partials (after kcpart dead)
    unsigned long long* refpart  = (unsigned long long*)big;       // after partials consumed
    float* dnn = (float*)(big + 4194304);                          // disjoint from refpart (2 MB)

    hipMemsetAsync(cntU, 0, (size_t)GM * 4, stream);
    k_counts2<<<dim3(49, BB), 256, 0, stream>>>(labels, cntU);

    if (!lowmem) {
        k_segsum7<false><<<dim3(NKC, 6, BB), 256, 0, stream>>>(feats, labels, kcpart);
        k_cvtmb<<<MM / 4, 256, 0, stream>>>(mb, mbh, yn);
        k_embfin2<<<GM, 64, 0, stream>>>(kcpart, cntU, emb, xn, embh);
        k_gemm<false><<<8192, 256, 0, stream>>>(embh, mbh, mb, xn, yn, partials);
    } else {
        hipMemsetAsync(emb, 0, SZ_EMB, stream);
        k_segsum7<true><<<dim3(NKC, 6, BB), 256, 0, stream>>>(feats, labels, emb);
        k_ynorm<<<MM / 4, 256, 0, stream>>>(mb, yn);
        k_embfin<<<GM, 64, 0, stream>>>(emb, cntU, xn, embh);
        k_gemm<true><<<8192, 256, 0, stream>>>(embh, embh, mb, xn, yn, partials);
    }

    k_reduce1<<<dim3(8, 8), 256, 0, stream>>>(partials, partial2);
    k_reduce2cand<<<BB, 256, 0, stream>>>(partial2, scores, locs, cand);
    k_refine<<<MM / RF_ROWS, 256, 0, stream>>>(emb, mb, xn, yn, cand, refpart);
    k_refred<<<32, 256, 0, stream>>>(refpart, keys2);
    k_final<<<1, 64, 0, stream>>>(keys2, cand, mp, scb, nn);
    k_dnn<<<MM / 4, 256, 0, stream>>>(mb, yn, nn, dnn);
    k_top9a<<<dim3(64, BB), 256, 0, stream>>>(dnn, t9v, t9i);
    k_top9b<<<BB, 256, 0, stream>>>(t9v, t9i, sup);
    k_pred<<<BB, 256, 0, stream>>>(emb, mb, yn, xn, mp, scb, sup, out + (size_t)BB * HWP);
    k_map<<<(BB * HWP) / 256, 256, 0, stream>>>(scores, labels, out);
}

// Round 10
// 681.836 us; speedup vs baseline: 1.7199x; 1.1238x over previous
//
#include <hip/hip_runtime.h>

#define BB 8
#define CC 384
#define HWP 50176
#define SS 256
#define MM 65536
#define TOPK 9
#define GM 2048          // BB*SS emb rows
#define NKC 16           // K-split blocks for segsum
#define RFB 2048         // refine blocks (32 m each)

typedef __attribute__((ext_vector_type(8))) __bf16 bf16x8;
typedef __attribute__((ext_vector_type(16))) float fx16;
typedef __attribute__((ext_vector_type(4))) float f32x4;

__device__ __forceinline__ unsigned short f2bf_rne(float x) {
    unsigned u = __float_as_uint(x);
    unsigned r = (u + 0x7FFFu + ((u >> 16) & 1u)) >> 16;
    return (unsigned short)r;
}

__device__ __forceinline__ bf16x8 pack8(float4 v0, float4 v1) {
    bf16x8 r;
    r[0] = (__bf16)v0.x; r[1] = (__bf16)v0.y; r[2] = (__bf16)v0.z; r[3] = (__bf16)v0.w;
    r[4] = (__bf16)v1.x; r[5] = (__bf16)v1.y; r[6] = (__bf16)v1.z; r[7] = (__bf16)v1.w;
    return r;
}

__device__ __forceinline__ void gl_lds16(const void* g, void* l) {
    auto gp = (const __attribute__((address_space(1))) unsigned int*)g;
    auto lp = (__attribute__((address_space(3))) unsigned int*)l;
    __builtin_amdgcn_global_load_lds(gp, lp, 16, 0, 0);
}

// ---------------- K1: per-(kc,b) label counts into slab (no memset, no global atomics) ----
__global__ void k_counts3(const int* __restrict__ labels, unsigned* __restrict__ cntS) {
    __shared__ unsigned cnt[SS];
    int kc = blockIdx.x, b = blockIdx.y;   // (49, 8)
    int t = threadIdx.x;
    cnt[t] = 0u;
    __syncthreads();
    int4 lv = ((const int4*)(labels + (size_t)b * HWP + kc * 1024))[t];
    atomicAdd(&cnt[lv.x], 1u);
    atomicAdd(&cnt[lv.y], 1u);
    atomicAdd(&cnt[lv.z], 1u);
    atomicAdd(&cnt[lv.w], 1u);
    __syncthreads();
    cntS[(kc * BB + b) * SS + t] = cnt[t];
}

// ---------------- K2: segment sums as MFMA GEMM (validated v7) ----------------
template <bool ATOMIC>
__global__ __launch_bounds__(256) void k_segsum7(const float* __restrict__ feats,
                                                 const int* __restrict__ labels,
                                                 float* __restrict__ outp) {
    __shared__ bf16x8 Fs[8][64];
    __shared__ int labL[64];
    int kc = blockIdx.x, cg = blockIdx.y, b = blockIdx.z;
    int t = threadIdx.x, l = t & 63, w = t >> 6;
    int c0b = cg * 64;
    int g16 = l >> 4;
    int rowl = l & 15;

    f32x4 acc[4][4];
#pragma unroll
    for (int i = 0; i < 4; i++)
#pragma unroll
        for (int j = 0; j < 4; j++) acc[i][j] = (f32x4){0.f, 0.f, 0.f, 0.f};

    const float* fb = feats + ((size_t)b * CC + c0b) * HWP;
    const int* lbase = labels + (size_t)b * HWP + kc * 3136;

    int id0 = t * 2;
    int cl = id0 >> 3, g0 = id0 & 7;
    const float* tbase = fb + (size_t)cl * HWP + kc * 3136 + g0 * 8;

    float4 ra0 = *(const float4*)(tbase + 0);
    float4 ra1 = *(const float4*)(tbase + 4);
    float4 rb0 = *(const float4*)(tbase + 8);
    float4 rb1 = *(const float4*)(tbase + 12);
    int4 rl4 = (t < 16) ? ((const int4*)lbase)[t] : (int4){0, 0, 0, 0};

    for (int tt = 0; tt < 49; tt++) {
        __syncthreads();
        if (t < 16) ((int4*)labL)[t] = rl4;
        Fs[g0][cl] = pack8(ra0, ra1);
        Fs[g0 + 1][cl] = pack8(rb0, rb1);
        if (tt + 1 < 49) {
            const float* nb_ = tbase + (size_t)(tt + 1) * 64;
            ra0 = *(const float4*)(nb_ + 0);
            ra1 = *(const float4*)(nb_ + 4);
            rb0 = *(const float4*)(nb_ + 8);
            rb1 = *(const float4*)(nb_ + 12);
            if (t < 16) rl4 = ((const int4*)(lbase + (tt + 1) * 64))[t];
        }
        __syncthreads();

        bf16x8 af0[4], af1[4];
#pragma unroll
        for (int rt = 0; rt < 4; rt++) {
            af0[rt] = Fs[g16][rt * 16 + rowl];
            af1[rt] = Fs[4 + g16][rt * 16 + rowl];
        }
        int4 lo0 = ((int4*)labL)[g16 * 2 + 0];
        int4 hi0 = ((int4*)labL)[g16 * 2 + 1];
        int4 lo1 = ((int4*)labL)[8 + g16 * 2 + 0];
        int4 hi1 = ((int4*)labL)[8 + g16 * 2 + 1];

#pragma unroll
        for (int st = 0; st < 4; st++) {
            int tgt = w * 64 + st * 16 + rowl;
            union { unsigned u[4]; bf16x8 v; } B;
            B.u[0] = (lo0.x == tgt ? 0x3F80u : 0u) | (lo0.y == tgt ? 0x3F800000u : 0u);
            B.u[1] = (lo0.z == tgt ? 0x3F80u : 0u) | (lo0.w == tgt ? 0x3F800000u : 0u);
            B.u[2] = (hi0.x == tgt ? 0x3F80u : 0u) | (hi0.y == tgt ? 0x3F800000u : 0u);
            B.u[3] = (hi0.z == tgt ? 0x3F80u : 0u) | (hi0.w == tgt ? 0x3F800000u : 0u);
#pragma unroll
            for (int rt = 0; rt < 4; rt++)
                acc[rt][st] = __builtin_amdgcn_mfma_f32_16x16x32_bf16(af0[rt], B.v, acc[rt][st], 0, 0, 0);
            B.u[0] = (lo1.x == tgt ? 0x3F80u : 0u) | (lo1.y == tgt ? 0x3F800000u : 0u);
            B.u[1] = (lo1.z == tgt ? 0x3F80u : 0u) | (lo1.w == tgt ? 0x3F800000u : 0u);
            B.u[2] = (hi1.x == tgt ? 0x3F80u : 0u) | (hi1.y == tgt ? 0x3F800000u : 0u);
            B.u[3] = (hi1.z == tgt ? 0x3F80u : 0u) | (hi1.w == tgt ? 0x3F800000u : 0u);
#pragma unroll
            for (int rt = 0; rt < 4; rt++)
                acc[rt][st] = __builtin_amdgcn_mfma_f32_16x16x32_bf16(af1[rt], B.v, acc[rt][st], 0, 0, 0);
        }
    }

    if (ATOMIC) {
#pragma unroll
        for (int rt = 0; rt < 4; rt++)
#pragma unroll
            for (int st = 0; st < 4; st++)
#pragma unroll
                for (int r = 0; r < 4; r++) {
                    int s = w * 64 + st * 16 + rowl;
                    int c = c0b + rt * 16 + g16 * 4 + r;
                    atomicAdd(&outp[((size_t)b * SS + s) * CC + c], acc[rt][st][r]);
                }
    } else {
        float* dst = outp + (size_t)(kc * BB + b) * SS * CC;
#pragma unroll
        for (int rt = 0; rt < 4; rt++)
#pragma unroll
            for (int st = 0; st < 4; st++)
#pragma unroll
                for (int r = 0; r < 4; r++) {
                    int s = w * 64 + st * 16 + rowl;
                    int c = c0b + rt * 16 + g16 * 4 + r;
                    dst[(size_t)s * CC + c] = acc[rt][st][r];
                }
    }
}

// ---------------- K3: bank fp32->bf16 + row norms, float4 vectorized ----------------
__global__ __launch_bounds__(256) void k_cvtmb2(const float* __restrict__ mb,
                                                unsigned short* __restrict__ mbh,
                                                float* __restrict__ yn) {
    int w = threadIdx.x >> 6, l = threadIdx.x & 63;
    int r0 = blockIdx.x * 16 + w * 4;
#pragma unroll
    for (int i = 0; i < 4; i++) {
        int row = r0 + i;
        const float4* src = (const float4*)(mb + (size_t)row * CC);   // 96 float4 per row
        float4 a = src[l];
        float4 b2 = {0.f, 0.f, 0.f, 0.f};
        if (l < 32) b2 = src[64 + l];
        ushort4 ua; ua.x = f2bf_rne(a.x); ua.y = f2bf_rne(a.y); ua.z = f2bf_rne(a.z); ua.w = f2bf_rne(a.w);
        ((ushort4*)(mbh + (size_t)row * CC))[l] = ua;
        if (l < 32) {
            ushort4 ub; ub.x = f2bf_rne(b2.x); ub.y = f2bf_rne(b2.y); ub.z = f2bf_rne(b2.z); ub.w = f2bf_rne(b2.w);
            ((ushort4*)(mbh + (size_t)row * CC))[64 + l] = ub;
        }
        float s = a.x * a.x + a.y * a.y + a.z * a.z + a.w * a.w
                + b2.x * b2.x + b2.y * b2.y + b2.z * b2.z + b2.w * b2.w;
#pragma unroll
        for (int m = 32; m; m >>= 1) s += __shfl_xor(s, m);
        if (l == 0) yn[row] = s;
    }
}

__global__ __launch_bounds__(256) void k_ynorm2(const float* __restrict__ mb, float* __restrict__ yn) {
    int w = threadIdx.x >> 6, l = threadIdx.x & 63;
    int r0 = blockIdx.x * 16 + w * 4;
#pragma unroll
    for (int i = 0; i < 4; i++) {
        int row = r0 + i;
        const float4* src = (const float4*)(mb + (size_t)row * CC);
        float4 a = src[l];
        float4 b2 = {0.f, 0.f, 0.f, 0.f};
        if (l < 32) b2 = src[64 + l];
        float s = a.x * a.x + a.y * a.y + a.z * a.z + a.w * a.w
                + b2.x * b2.x + b2.y * b2.y + b2.z * b2.z + b2.w * b2.w;
#pragma unroll
        for (int m = 32; m; m >>= 1) s += __shfl_xor(s, m);
        if (l == 0) yn[row] = s;
    }
}

// ---------------- K4a: reduce kc-partials + counts -> emb/xn/embh (float4) ----------------
__global__ __launch_bounds__(256) void k_embfin3(const float* __restrict__ kcpart,
                                                 const unsigned* __restrict__ cntS,
                                                 float* __restrict__ emb, float* __restrict__ xn,
                                                 unsigned short* __restrict__ embh) {
    int w = threadIdx.x >> 6, l = threadIdx.x & 63;
    int i = blockIdx.x * 4 + w;           // row 0..2047
    int b = i >> 8, s256 = i & 255;
    float4 a0 = {0.f, 0.f, 0.f, 0.f}, a1 = {0.f, 0.f, 0.f, 0.f};
#pragma unroll 4
    for (int kc = 0; kc < NKC; kc++) {
        const float4* row = (const float4*)(kcpart + ((size_t)(kc * BB + b) * SS + s256) * CC);
        float4 v = row[l];
        a0.x += v.x; a0.y += v.y; a0.z += v.z; a0.w += v.w;
        if (l < 32) {
            float4 v1 = row[64 + l];
            a1.x += v1.x; a1.y += v1.y; a1.z += v1.z; a1.w += v1.w;
        }
    }
    // count = sum over 49 kc slabs
    float cw = (l < 49) ? (float)cntS[(l * BB + b) * SS + s256] : 0.f;
#pragma unroll
    for (int m = 32; m; m >>= 1) cw += __shfl_xor(cw, m);
    float inv = 1.f / fmaxf(cw, 1.f);

    a0.x *= inv; a0.y *= inv; a0.z *= inv; a0.w *= inv;
    a1.x *= inv; a1.y *= inv; a1.z *= inv; a1.w *= inv;
    ((float4*)(emb + (size_t)i * CC))[l] = a0;
    ushort4 u0; u0.x = f2bf_rne(a0.x); u0.y = f2bf_rne(a0.y); u0.z = f2bf_rne(a0.z); u0.w = f2bf_rne(a0.w);
    ((ushort4*)(embh + (size_t)i * CC))[l] = u0;
    if (l < 32) {
        ((float4*)(emb + (size_t)i * CC))[64 + l] = a1;
        ushort4 u1; u1.x = f2bf_rne(a1.x); u1.y = f2bf_rne(a1.y); u1.z = f2bf_rne(a1.z); u1.w = f2bf_rne(a1.w);
        ((ushort4*)(embh + (size_t)i * CC))[64 + l] = u1;
    }
    float ss = a0.x * a0.x + a0.y * a0.y + a0.z * a0.z + a0.w * a0.w
             + a1.x * a1.x + a1.y * a1.y + a1.z * a1.z + a1.w * a1.w;
#pragma unroll
    for (int m = 32; m; m >>= 1) ss += __shfl_xor(ss, m);
    if (l == 0) xn[i] = ss;
}

// ---------------- K4b: finalize emb in place (lowmem path) ----------------
__global__ __launch_bounds__(256) void k_embfin_lm(float* __restrict__ emb,
                                                   const unsigned* __restrict__ cntS,
                                                   float* __restrict__ xn,
                                                   unsigned short* __restrict__ embh) {
    int w = threadIdx.x >> 6, l = threadIdx.x & 63;
    int i = blockIdx.x * 4 + w;
    int b = i >> 8, s256 = i & 255;
    float4* e4 = (float4*)(emb + (size_t)i * CC);
    float4 a0 = e4[l];
    float4 a1 = {0.f, 0.f, 0.f, 0.f};
    if (l < 32) a1 = e4[64 + l];
    float cw = (l < 49) ? (float)cntS[(l * BB + b) * SS + s256] : 0.f;
#pragma unroll
    for (int m = 32; m; m >>= 1) cw += __shfl_xor(cw, m);
    float inv = 1.f / fmaxf(cw, 1.f);
    a0.x *= inv; a0.y *= inv; a0.z *= inv; a0.w *= inv;
    a1.x *= inv; a1.y *= inv; a1.z *= inv; a1.w *= inv;
    e4[l] = a0;
    ushort4 u0; u0.x = f2bf_rne(a0.x); u0.y = f2bf_rne(a0.y); u0.z = f2bf_rne(a0.z); u0.w = f2bf_rne(a0.w);
    ((ushort4*)(embh + (size_t)i * CC))[l] = u0;
    if (l < 32) {
        e4[64 + l] = a1;
        ushort4 u1; u1.x = f2bf_rne(a1.x); u1.y = f2bf_rne(a1.y); u1.z = f2bf_rne(a1.z); u1.w = f2bf_rne(a1.w);
        ((ushort4*)(embh + (size_t)i * CC))[64 + l] = u1;
    }
    float ss = a0.x * a0.x + a0.y * a0.y + a0.z * a0.z + a0.w * a0.w
             + a1.x * a1.x + a1.y * a1.y + a1.z * a1.z + a1.w * a1.w;
#pragma unroll
    for (int m = 32; m; m >>= 1) ss += __shfl_xor(ss, m);
    if (l == 0) xn[i] = ss;
}

// ---------------- K5: 128x128 bf16 MFMA GEMM + fused row-min (u32 keys) ----------------
template <bool REGB>
__global__ __launch_bounds__(256) void k_gemm(
        const unsigned short* __restrict__ Ah, const unsigned short* __restrict__ Bh,
        const float* __restrict__ Bf,
        const float* __restrict__ xn, const float* __restrict__ yn,
        unsigned* __restrict__ partials) {
    __shared__ bf16x8 As[8][128];
    __shared__ bf16x8 Bs[8][128];
    __shared__ unsigned rowbest[128];
    int bid = blockIdx.x;
    int swz = (bid & 7) * 1024 + (bid >> 3);
    int rb = swz & 15, nb = swz >> 4;
    int t = threadIdx.x;
    int w = t >> 6, l = t & 63;
    int wm = w & 1, wn = w >> 1;

    if (t < 128) rowbest[t] = 0xFFFFFFFFu;

    fx16 acc00, acc01, acc10, acc11;
#pragma unroll
    for (int p = 0; p < 16; p++) { acc00[p] = 0.f; acc01[p] = 0.f; acc10[p] = 0.f; acc11[p] = 0.f; }

    const unsigned short* Abase = Ah + (size_t)(rb * 128) * CC;
    const unsigned short* Bbase = REGB ? nullptr : (Bh + (size_t)(nb * 128) * CC);
    const float* Bfbase = Bf + (size_t)(nb * 128) * CC;

    for (int kt = 0; kt < 6; kt++) {
        int k0 = kt * 64;
#pragma unroll
        for (int q = 0; q < 4; q++) {
            int c = q * 256 + t;
            int r = c & 127, g = c >> 7;
            gl_lds16(Abase + (size_t)r * CC + k0 + g * 8, &As[g][r]);
            if (!REGB) {
                gl_lds16(Bbase + (size_t)r * CC + k0 + g * 8, &Bs[g][r]);
            } else {
                const float* src = Bfbase + (size_t)r * CC + k0 + g * 8;
                float4 v0 = *(const float4*)(src);
                float4 v1 = *(const float4*)(src + 4);
                Bs[g][r] = pack8(v0, v1);
            }
        }
        __syncthreads();
#pragma unroll
        for (int s = 0; s < 4; s++) {
            int g = s * 2 + (l >> 5);
            bf16x8 a0 = As[g][wm * 64 + (l & 31)];
            bf16x8 a1 = As[g][wm * 64 + 32 + (l & 31)];
            bf16x8 b0 = Bs[g][wn * 64 + (l & 31)];
            bf16x8 b1 = Bs[g][wn * 64 + 32 + (l & 31)];
            acc00 = __builtin_amdgcn_mfma_f32_32x32x16_bf16(a0, b0, acc00, 0, 0, 0);
            acc01 = __builtin_amdgcn_mfma_f32_32x32x16_bf16(a0, b1, acc01, 0, 0, 0);
            acc10 = __builtin_amdgcn_mfma_f32_32x32x16_bf16(a1, b0, acc10, 0, 0, 0);
            acc11 = __builtin_amdgcn_mfma_f32_32x32x16_bf16(a1, b1, acc11, 0, 0, 0);
        }
        __syncthreads();
    }

    int coll0 = wn * 64 + (l & 31);
    int coll1 = coll0 + 32;
    float yn0 = yn[nb * 128 + coll0], yn1 = yn[nb * 128 + coll1];
#pragma unroll
    for (int i = 0; i < 2; i++) {
#pragma unroll
        for (int p = 0; p < 16; p++) {
            float a0v = (i == 0) ? acc00[p] : acc10[p];
            float a1v = (i == 0) ? acc01[p] : acc11[p];
            int rl = i * 32 + (p & 3) + 8 * (p >> 2) + 4 * (l >> 5);
            float xr = xn[rb * 128 + wm * 64 + rl];
            float d0 = fmaxf(xr - 2.f * a0v + yn0, 0.f);
            float d1 = fmaxf(xr - 2.f * a1v + yn1, 0.f);
            unsigned k0 = (__float_as_uint(d0) & 0xFFFFFF00u) | (unsigned)coll0;
            unsigned k1 = (__float_as_uint(d1) & 0xFFFFFF00u) | (unsigned)coll1;
            unsigned best = k0 < k1 ? k0 : k1;
#pragma unroll
            for (int m = 1; m < 32; m <<= 1) {
                unsigned o2 = __shfl_xor(best, m);
                if (o2 < best) best = o2;
            }
            if ((l & 31) == 0) atomicMin(&rowbest[wm * 64 + rl], best);
        }
    }
    __syncthreads();
    if (t < 128) partials[(size_t)nb * GM + rb * 128 + t] = rowbest[t];
}

// ---------------- K6: expand u32 keys -> u64 global, min over 64 nb ----------------
__global__ void k_reduce1(const unsigned* __restrict__ partials,
                          unsigned long long* __restrict__ partial2) {
    int row = blockIdx.x * 256 + threadIdx.x;
    int ng = blockIdx.y;
    unsigned long long m = ~0ull;
    for (int n = 0; n < 64; n++) {
        int nb = ng * 64 + n;
        unsigned k = partials[(size_t)nb * GM + row];
        unsigned long long v = ((unsigned long long)(k & 0xFFFFFF00u) << 32)
                             | (unsigned)(nb * 128 + (k & 0xFFu));
        if (v < m) m = v;
    }
    partial2[ng * GM + row] = m;
}

// ---------------- K7: final min + scores + per-batch top-4 candidates ----------------
__global__ void k_reduce2cand(const unsigned long long* __restrict__ partial2,
                              float* __restrict__ scores, int* __restrict__ locs,
                              int* __restrict__ cand) {
    __shared__ unsigned long long key[256];
    __shared__ unsigned long long red[256];
    int b = blockIdx.x, t = threadIdx.x;
    int row = b * 256 + t;
    unsigned long long m = ~0ull;
    for (int g = 0; g < 8; g++) {
        unsigned long long v = partial2[g * GM + row];
        if (v < m) m = v;
    }
    float sc = sqrtf(__uint_as_float((unsigned)(m >> 32)));
    scores[row] = sc;
    locs[row] = (int)(m & 0xffffffffu);
    key[t] = ((unsigned long long)__float_as_uint(sc) << 32) | (unsigned)(255 - t);
    __syncthreads();
    for (int k = 0; k < 4; k++) {
        red[t] = key[t];
        __syncthreads();
        for (int s = 128; s; s >>= 1) {
            if (t < s && red[t + s] > red[t]) red[t] = red[t + s];
            __syncthreads();
        }
        unsigned long long win = red[0];
        int patch = 255 - (int)(win & 0xffffffffu);
        if (t == 0) cand[b * 4 + k] = b * SS + patch;
        __syncthreads();
        if (t == patch) key[t] = 0;
        __syncthreads();
    }
}

// ---------------- K9: exact fp32 re-search, register-best (no LDS atomics) ----------------
__global__ __launch_bounds__(256) void k_refine2(
        const float* __restrict__ emb, const float* __restrict__ mb,
        const float* __restrict__ xn, const float* __restrict__ yn,
        const int* __restrict__ cand, unsigned long long* __restrict__ refpart) {
    __shared__ float cl[32 * CC];
    __shared__ float xnc[32];
    __shared__ int cr[32];
    __shared__ unsigned long long wbest[4][32];
    int t = threadIdx.x, w = t >> 6, l = t & 63;
    if (t < 32) cr[t] = cand[t];
    __syncthreads();
    if (t < 32) xnc[t] = xn[cr[t]];
    for (int i = t; i < 32 * CC; i += 256) {
        int j = i / CC, p = i - j * CC;
        cl[i] = emb[(size_t)cr[j] * CC + p];
    }
    __syncthreads();

    unsigned long long best = ~0ull;
#pragma unroll
    for (int g = 0; g < 4; g++) {
        int m0 = blockIdx.x * 32 + g * 8 + w * 2, m1 = m0 + 1;
        float2 r0[3], r1[3];
#pragma unroll
        for (int c = 0; c < 3; c++) {
            r0[c] = *(const float2*)&mb[(size_t)m0 * CC + c * 128 + l * 2];
            r1[c] = *(const float2*)&mb[(size_t)m1 * CC + c * 128 + l * 2];
        }
        float ya = yn[m0], yb = yn[m1];
#pragma unroll 2
        for (int j = 0; j < 32; j++) {
            float s0 = 0.f, s1 = 0.f;
#pragma unroll
            for (int c = 0; c < 3; c++) {
                float2 cv = *(const float2*)&cl[j * CC + c * 128 + l * 2];
                s0 = fmaf(r0[c].x, cv.x, s0); s0 = fmaf(r0[c].y, cv.y, s0);
                s1 = fmaf(r1[c].x, cv.x, s1); s1 = fmaf(r1[c].y, cv.y, s1);
            }
#pragma unroll
            for (int mm = 32; mm; mm >>= 1) { s0 += __shfl_xor(s0, mm); s1 += __shfl_xor(s1, mm); }
            float d0 = fmaxf(xnc[j] - 2.f * s0 + ya, 0.f);
            float d1 = fmaxf(xnc[j] - 2.f * s1 + yb, 0.f);
            unsigned long long k0 = ((unsigned long long)__float_as_uint(d0) << 32) | (unsigned)m0;
            unsigned long long k1 = ((unsigned long long)__float_as_uint(d1) << 32) | (unsigned)m1;
            unsigned long long kb = k0 < k1 ? k0 : k1;
            if (l == j && kb < best) best = kb;   // lane j owns candidate j's running min
        }
    }
    if (l < 32) wbest[w][l] = best;
    __syncthreads();
    if (t < 32) {
        unsigned long long m = wbest[0][t];
        if (wbest[1][t] < m) m = wbest[1][t];
        if (wbest[2][t] < m) m = wbest[2][t];
        if (wbest[3][t] < m) m = wbest[3][t];
        refpart[(size_t)blockIdx.x * 32 + t] = m;
    }
}

__global__ void k_refred(const unsigned long long* __restrict__ refpart,
                         unsigned long long* __restrict__ keys2) {
    __shared__ unsigned long long red[256];
    int j = blockIdx.x, t = threadIdx.x;
    unsigned long long m = ~0ull;
    for (int i = t; i < RFB; i += 256) {
        unsigned long long v = refpart[(size_t)i * 32 + j];
        if (v < m) m = v;
    }
    red[t] = m;
    __syncthreads();
    for (int s = 128; s; s >>= 1) {
        if (t < s && red[t + s] < red[t]) red[t] = red[t + s];
        __syncthreads();
    }
    if (t == 0) keys2[j] = red[0];
}

__global__ void k_final(const unsigned long long* __restrict__ keys2, const int* __restrict__ cand,
                        int* __restrict__ mp, float* __restrict__ scb, int* __restrict__ nn) {
    int b = threadIdx.x;
    if (b < BB) {
        float bestsc = -1.f;
        int bestpatch = 1 << 20, bestnn = 0;
        for (int k = 0; k < 4; k++) {
            unsigned long long key = keys2[b * 4 + k];
            float sc = sqrtf(__uint_as_float((unsigned)(key >> 32)));
            int patch = cand[b * 4 + k] & 255;
            int nnidx = (int)(key & 0xffffffffu);
            if (sc > bestsc || (sc == bestsc && patch < bestpatch)) {
                bestsc = sc; bestpatch = patch; bestnn = nnidx;
            }
        }
        mp[b] = bestpatch; scb[b] = bestsc; nn[b] = bestnn;
    }
}

// ---------------- K12: d_nn, float4 loads, 16 m per block ----------------
__global__ __launch_bounds__(256) void k_dnn2(const float* __restrict__ mb,
                                              const float* __restrict__ yn,
                                              const int* __restrict__ nn,
                                              float* __restrict__ dnn) {
    __shared__ float nnf[BB][CC];
    __shared__ float ynn[BB];
    int t = threadIdx.x, w = t >> 6, l = t & 63;
    for (int i = t; i < BB * CC; i += 256) {
        int bb = i / CC, cc = i - bb * CC;
        nnf[bb][cc] = mb[(size_t)nn[bb] * CC + cc];
    }
    if (t < BB) ynn[t] = yn[nn[t]];
    __syncthreads();
#pragma unroll
    for (int i = 0; i < 4; i++) {
        int m = blockIdx.x * 16 + w * 4 + i;
        const float4* r4 = (const float4*)(mb + (size_t)m * CC);
        float4 va = r4[l];
        float4 vb = {0.f, 0.f, 0.f, 0.f};
        if (l < 32) vb = r4[64 + l];
        float ym = yn[m];
#pragma unroll
        for (int b = 0; b < BB; b++) {
            const float4* n4 = (const float4*)nnf[b];
            float4 na = n4[l];
            float s = va.x * na.x + va.y * na.y + va.z * na.z + va.w * na.w;
            if (l < 32) {
                float4 nb2 = n4[64 + l];
                s += vb.x * nb2.x + vb.y * nb2.y + vb.z * nb2.z + vb.w * nb2.w;
            }
#pragma unroll
            for (int mm = 32; mm; mm >>= 1) s += __shfl_xor(s, mm);
            if (l == 0) {
                float d2 = fmaxf(ynn[b] - 2.f * s + ym, 0.f);
                dnn[(size_t)b * MM + m] = sqrtf(d2);
            }
        }
    }
}

// ---------------- K13a: per-chunk top-9 (64 chunks x 8 batches) ----------------
__global__ void k_top9a(const float* __restrict__ dnn, float* __restrict__ t9v,
                        int* __restrict__ t9i) {
    __shared__ float sd[256][TOPK];
    __shared__ int sx[256][TOPK];
    int c = blockIdx.x, b = blockIdx.y, t = threadIdx.x;
    float ld[TOPK];
    int li[TOPK];
#pragma unroll
    for (int k = 0; k < TOPK; k++) { ld[k] = INFINITY; li[k] = MM; }
    const float* d = dnn + (size_t)b * MM;
    for (int m = c * 1024 + t; m < (c + 1) * 1024; m += 256) {
        float v = d[m];
        if (v < ld[TOPK - 1] || (v == ld[TOPK - 1] && m < li[TOPK - 1])) {
            int k = TOPK - 1;
            while (k > 0 && (v < ld[k - 1] || (v == ld[k - 1] && m < li[k - 1]))) {
                ld[k] = ld[k - 1]; li[k] = li[k - 1]; k--;
            }
            ld[k] = v; li[k] = m;
        }
    }
    for (int k = 0; k < TOPK; k++) { sd[t][k] = ld[k]; sx[t][k] = li[k]; }
    __syncthreads();
    for (int s = 128; s; s >>= 1) {
        if (t < s) {
            float md[TOPK]; int mi[TOPK];
            int p = 0, q = 0;
            for (int k = 0; k < TOPK; k++) {
                float va = sd[t][p], vb = sd[t + s][q];
                int ia = sx[t][p], ib = sx[t + s][q];
                bool ta = (va < vb) || (va == vb && ia < ib);
                if (ta) { md[k] = va; mi[k] = ia; p++; }
                else    { md[k] = vb; mi[k] = ib; q++; }
            }
            for (int k = 0; k < TOPK; k++) { sd[t][k] = md[k]; sx[t][k] = mi[k]; }
        }
        __syncthreads();
    }
    if (t < TOPK) {
        t9v[(b * 64 + c) * TOPK + t] = sd[0][t];
        t9i[(b * 64 + c) * TOPK + t] = sx[0][t];
    }
}

// ---------------- K13b+K14: merge top-9 + pred_score (fused) ----------------
__global__ void k_fintop(const float* __restrict__ t9v, const int* __restrict__ t9i,
                         const float* __restrict__ emb, const float* __restrict__ mb,
                         const float* __restrict__ yn, const float* __restrict__ xn,
                         const int* __restrict__ mp, const float* __restrict__ scb,
                         float* __restrict__ outp) {
    __shared__ float sd[256][TOPK];
    __shared__ int sx[256][TOPK];
    __shared__ int supl[TOPK];
    __shared__ float ds[TOPK];
    int b = blockIdx.x, t = threadIdx.x;
    float ld[TOPK];
    int li[TOPK];
#pragma unroll
    for (int k = 0; k < TOPK; k++) { ld[k] = INFINITY; li[k] = MM; }
    for (int i = t; i < 64 * TOPK; i += 256) {
        float v = t9v[b * 64 * TOPK + i];
        int m = t9i[b * 64 * TOPK + i];
        if (v < ld[TOPK - 1] || (v == ld[TOPK - 1] && m < li[TOPK - 1])) {
            int k = TOPK - 1;
            while (k > 0 && (v < ld[k - 1] || (v == ld[k - 1] && m < li[k - 1]))) {
                ld[k] = ld[k - 1]; li[k] = li[k - 1]; k--;
            }
            ld[k] = v; li[k] = m;
        }
    }
    for (int k = 0; k < TOPK; k++) { sd[t][k] = ld[k]; sx[t][k] = li[k]; }
    __syncthreads();
    for (int s = 128; s; s >>= 1) {
        if (t < s) {
            float md[TOPK]; int mi[TOPK];
            int p = 0, q = 0;
            for (int k = 0; k < TOPK; k++) {
                float va = sd[t][p], vb = sd[t + s][q];
                int ia = sx[t][p], ib = sx[t + s][q];
                bool ta = (va < vb) || (va == vb && ia < ib);
                if (ta) { md[k] = va; mi[k] = ia; p++; }
                else    { md[k] = vb; mi[k] = ib; q++; }
            }
            for (int k = 0; k < TOPK; k++) { sd[t][k] = md[k]; sx[t][k] = mi[k]; }
        }
        __syncthreads();
    }
    if (t < TOPK) supl[t] = sx[0][t];
    __syncthreads();

    // pred phase
    int w = t >> 6, l = t & 63;
    int mpb = mp[b];
    const float* mf = emb + ((size_t)b * SS + mpb) * CC;
    float xr = xn[b * SS + mpb];
    for (int k = w; k < TOPK; k += 4) {
        int sidx = supl[k];
        const float* sr = mb + (size_t)sidx * CC;
        float s = 0.f;
#pragma unroll
        for (int i = 0; i < 6; i++) s = fmaf(mf[i * 64 + l], sr[i * 64 + l], s);
#pragma unroll
        for (int mm = 32; mm; mm >>= 1) s += __shfl_xor(s, mm);
        if (l == 0) ds[k] = sqrtf(fmaxf(xr - 2.f * s + yn[sidx], 0.f));
    }
    __syncthreads();
    if (t == 0) {
        float mx = ds[0];
        for (int k = 1; k < TOPK; k++) mx = fmaxf(mx, ds[k]);
        float num = expf(ds[0] - mx), den = 0.f;
        for (int k = 0; k < TOPK; k++) den += expf(ds[k] - mx);
        outp[b] = (1.f - num / den) * scb[b];
    }
}

// ---------------- K15: anomaly map scatter (int4/float4) ----------------
__global__ void k_map4(const float* __restrict__ scores, const int* __restrict__ labels,
                       float* __restrict__ out) {
    size_t i4 = (size_t)blockIdx.x * 256 + threadIdx.x;   // over B*HW/4
    int b = (int)(i4 / (HWP / 4));
    int4 lv = ((const int4*)labels)[i4];
    const float* sb = scores + b * SS;
    float4 o;
    o.x = sb[lv.x]; o.y = sb[lv.y]; o.z = sb[lv.z]; o.w = sb[lv.w];
    ((float4*)out)[i4] = o;
}

extern "C" void kernel_launch(void* const* d_in, const int* in_sizes, int n_in,
                              void* d_out, int out_size, void* d_ws, size_t ws_size,
                              hipStream_t stream) {
    const float* feats  = (const float*)d_in[0];
    const int*   labels = (const int*)d_in[1];
    const float* mb     = (const float*)d_in[2];
    float* out = (float*)d_out;

    char* ws = (char*)d_ws;
    const size_t SZ_MBH   = (size_t)MM * CC * 2;              // 50.3 MB
    const size_t SZ_EMBH  = (size_t)GM * CC * 2;
    const size_t SZ_EMB   = (size_t)GM * CC * 4;
    const size_t SZ_YN    = (size_t)MM * 4;
    const size_t SZ_SMALL = 8192;
    const size_t SZ_CNTS  = (size_t)49 * BB * SS * 4;         // 401 KB
    const size_t SZ_P2    = (size_t)8 * GM * 8;
    const size_t SZ_T9    = (size_t)BB * 64 * TOPK * 4;
    const size_t SZ_KCP   = (size_t)NKC * BB * SS * CC * 4;   // 50.3 MB
    const size_t SZ_BIG   = SZ_KCP;

    size_t need_full = SZ_MBH + SZ_EMBH + SZ_EMB + SZ_YN + 3 * SZ_SMALL + SZ_CNTS + 2048
                     + SZ_P2 + 2 * SZ_T9 + SZ_BIG + 1024;
    bool lowmem = ws_size < need_full;

    size_t o = 0;
    unsigned short* mbh = nullptr;
    if (!lowmem) { mbh = (unsigned short*)(ws + o); o += SZ_MBH; }
    unsigned short* embh = (unsigned short*)(ws + o); o += SZ_EMBH;
    float* emb = (float*)(ws + o);                    o += SZ_EMB;
    float* yn  = (float*)(ws + o);                    o += SZ_YN;
    float* xn  = (float*)(ws + o);                    o += SZ_SMALL;
    float* scores = (float*)(ws + o);                 o += SZ_SMALL;
    int*   locs   = (int*)(ws + o);                   o += SZ_SMALL;
    unsigned* cntS = (unsigned*)(ws + o);             o += SZ_CNTS;
    int*   cand   = (int*)(ws + o);                   o += 256;
    unsigned long long* keys2 = (unsigned long long*)(ws + o); o += 256;
    int*   mp  = (int*)(ws + o);                      o += 128;
    float* scb = (float*)(ws + o);                    o += 128;
    int*   nn  = (int*)(ws + o);                      o += 128;
    o = (o + 255) & ~(size_t)255;
    float* t9v = (float*)(ws + o);                    o += SZ_T9;
    int*   t9i = (int*)(ws + o);                      o += SZ_T9;
    o = (o + 255) & ~(size_t)255;
    unsigned long long* partial2 = (unsigned long long*)(ws + o); o += SZ_P2;
    char* big = ws + o;
    float* kcpart = (float*)big;                                   // segsum partials
    unsigned* partials = (unsigned*)big;                           // gemm u32 partials (after kcpart dead)
    unsigned long long* refpart  = (unsigned long long*)big;       // after partials consumed (512 KB)
    float* dnn = (float*)(big + 4194304);                          // disjoint from refpart

    k_counts3<<<dim3(49, BB), 256, 0, stream>>>(labels, cntS);

    if (!lowmem) {
        k_segsum7<false><<<dim3(NKC, 6, BB), 256, 0, stream>>>(feats, labels, kcpart);
        k_cvtmb2<<<MM / 16, 256, 0, stream>>>(mb, mbh, yn);
        k_embfin3<<<GM / 4, 256, 0, stream>>>(kcpart, cntS, emb, xn, embh);
        k_gemm<false><<<8192, 256, 0, stream>>>(embh, mbh, mb, xn, yn, partials);
    } else {
        hipMemsetAsync(emb, 0, SZ_EMB, stream);
        k_segsum7<true><<<dim3(NKC, 6, BB), 256, 0, stream>>>(feats, labels, emb);
        k_ynorm2<<<MM / 16, 256, 0, stream>>>(mb, yn);
        k_embfin_lm<<<GM / 4, 256, 0, stream>>>(emb, cntS, xn, embh);
        k_gemm<true><<<8192, 256, 0, stream>>>(embh, embh, mb, xn, yn, partials);
    }

    k_reduce1<<<dim3(8, 8), 256, 0, stream>>>(partials, partial2);
    k_reduce2cand<<<BB, 256, 0, stream>>>(partial2, scores, locs, cand);
    k_refine2<<<RFB, 256, 0, stream>>>(emb, mb, xn, yn, cand, refpart);
    k_refred<<<32, 256, 0, stream>>>(refpart, keys2);
    k_final<<<1, 64, 0, stream>>>(keys2, cand, mp, scb, nn);
    k_dnn2<<<MM / 16, 256, 0, stream>>>(mb, yn, nn, dnn);
    k_top9a<<<dim3(64, BB), 256, 0, stream>>>(dnn, t9v, t9i);
    k_fintop<<<BB, 256, 0, stream>>>(t9v, t9i, emb, mb, yn, xn, mp, scb, out + (size_t)BB * HWP);
    k_map4<<<(BB * HWP / 4) / 256, 256, 0, stream>>>(scores, labels, out);
}

// Round 11
// 613.389 us; speedup vs baseline: 1.9118x; 1.1116x over previous
//
#include <hip/hip_runtime.h>

#define BB 8
#define CC 384
#define HWP 50176
#define SS 256
#define MM 65536
#define TOPK 9
#define GM 2048          // BB*SS emb rows
#define NKC 16           // K-split blocks for segsum
#define RFB3 1024        // refine blocks (64 m each)

typedef __attribute__((ext_vector_type(8))) __bf16 bf16x8;
typedef __attribute__((ext_vector_type(16))) float fx16;
typedef __attribute__((ext_vector_type(4))) float f32x4;

__device__ __forceinline__ unsigned short f2bf_rne(float x) {
    unsigned u = __float_as_uint(x);
    unsigned r = (u + 0x7FFFu + ((u >> 16) & 1u)) >> 16;
    return (unsigned short)r;
}

__device__ __forceinline__ bf16x8 pack8(float4 v0, float4 v1) {
    bf16x8 r;
    r[0] = (__bf16)v0.x; r[1] = (__bf16)v0.y; r[2] = (__bf16)v0.z; r[3] = (__bf16)v0.w;
    r[4] = (__bf16)v1.x; r[5] = (__bf16)v1.y; r[6] = (__bf16)v1.z; r[7] = (__bf16)v1.w;
    return r;
}

__device__ __forceinline__ void gl_lds16(const void* g, void* l) {
    auto gp = (const __attribute__((address_space(1))) unsigned int*)g;
    auto lp = (__attribute__((address_space(3))) unsigned int*)l;
    __builtin_amdgcn_global_load_lds(gp, lp, 16, 0, 0);
}

// ---------------- K1: per-(kc,b) label counts into slab ----------------
__global__ void k_counts3(const int* __restrict__ labels, unsigned* __restrict__ cntS) {
    __shared__ unsigned cnt[SS];
    int kc = blockIdx.x, b = blockIdx.y;   // (49, 8)
    int t = threadIdx.x;
    cnt[t] = 0u;
    __syncthreads();
    int4 lv = ((const int4*)(labels + (size_t)b * HWP + kc * 1024))[t];
    atomicAdd(&cnt[lv.x], 1u);
    atomicAdd(&cnt[lv.y], 1u);
    atomicAdd(&cnt[lv.z], 1u);
    atomicAdd(&cnt[lv.w], 1u);
    __syncthreads();
    cntS[(kc * BB + b) * SS + t] = cnt[t];
}

// ---------------- K2: segment sums as MFMA GEMM (validated v7) ----------------
template <bool ATOMIC>
__global__ __launch_bounds__(256) void k_segsum7(const float* __restrict__ feats,
                                                 const int* __restrict__ labels,
                                                 float* __restrict__ outp) {
    __shared__ bf16x8 Fs[8][64];
    __shared__ int labL[64];
    int kc = blockIdx.x, cg = blockIdx.y, b = blockIdx.z;
    int t = threadIdx.x, l = t & 63, w = t >> 6;
    int c0b = cg * 64;
    int g16 = l >> 4;
    int rowl = l & 15;

    f32x4 acc[4][4];
#pragma unroll
    for (int i = 0; i < 4; i++)
#pragma unroll
        for (int j = 0; j < 4; j++) acc[i][j] = (f32x4){0.f, 0.f, 0.f, 0.f};

    const float* fb = feats + ((size_t)b * CC + c0b) * HWP;
    const int* lbase = labels + (size_t)b * HWP + kc * 3136;

    int id0 = t * 2;
    int cl = id0 >> 3, g0 = id0 & 7;
    const float* tbase = fb + (size_t)cl * HWP + kc * 3136 + g0 * 8;

    float4 ra0 = *(const float4*)(tbase + 0);
    float4 ra1 = *(const float4*)(tbase + 4);
    float4 rb0 = *(const float4*)(tbase + 8);
    float4 rb1 = *(const float4*)(tbase + 12);
    int4 rl4 = (t < 16) ? ((const int4*)lbase)[t] : (int4){0, 0, 0, 0};

    for (int tt = 0; tt < 49; tt++) {
        __syncthreads();
        if (t < 16) ((int4*)labL)[t] = rl4;
        Fs[g0][cl] = pack8(ra0, ra1);
        Fs[g0 + 1][cl] = pack8(rb0, rb1);
        if (tt + 1 < 49) {
            const float* nb_ = tbase + (size_t)(tt + 1) * 64;
            ra0 = *(const float4*)(nb_ + 0);
            ra1 = *(const float4*)(nb_ + 4);
            rb0 = *(const float4*)(nb_ + 8);
            rb1 = *(const float4*)(nb_ + 12);
            if (t < 16) rl4 = ((const int4*)(lbase + (tt + 1) * 64))[t];
        }
        __syncthreads();

        bf16x8 af0[4], af1[4];
#pragma unroll
        for (int rt = 0; rt < 4; rt++) {
            af0[rt] = Fs[g16][rt * 16 + rowl];
            af1[rt] = Fs[4 + g16][rt * 16 + rowl];
        }
        int4 lo0 = ((int4*)labL)[g16 * 2 + 0];
        int4 hi0 = ((int4*)labL)[g16 * 2 + 1];
        int4 lo1 = ((int4*)labL)[8 + g16 * 2 + 0];
        int4 hi1 = ((int4*)labL)[8 + g16 * 2 + 1];

#pragma unroll
        for (int st = 0; st < 4; st++) {
            int tgt = w * 64 + st * 16 + rowl;
            union { unsigned u[4]; bf16x8 v; } B;
            B.u[0] = (lo0.x == tgt ? 0x3F80u : 0u) | (lo0.y == tgt ? 0x3F800000u : 0u);
            B.u[1] = (lo0.z == tgt ? 0x3F80u : 0u) | (lo0.w == tgt ? 0x3F800000u : 0u);
            B.u[2] = (hi0.x == tgt ? 0x3F80u : 0u) | (hi0.y == tgt ? 0x3F800000u : 0u);
            B.u[3] = (hi0.z == tgt ? 0x3F80u : 0u) | (hi0.w == tgt ? 0x3F800000u : 0u);
#pragma unroll
            for (int rt = 0; rt < 4; rt++)
                acc[rt][st] = __builtin_amdgcn_mfma_f32_16x16x32_bf16(af0[rt], B.v, acc[rt][st], 0, 0, 0);
            B.u[0] = (lo1.x == tgt ? 0x3F80u : 0u) | (lo1.y == tgt ? 0x3F800000u : 0u);
            B.u[1] = (lo1.z == tgt ? 0x3F80u : 0u) | (lo1.w == tgt ? 0x3F800000u : 0u);
            B.u[2] = (hi1.x == tgt ? 0x3F80u : 0u) | (hi1.y == tgt ? 0x3F800000u : 0u);
            B.u[3] = (hi1.z == tgt ? 0x3F80u : 0u) | (hi1.w == tgt ? 0x3F800000u : 0u);
#pragma unroll
            for (int rt = 0; rt < 4; rt++)
                acc[rt][st] = __builtin_amdgcn_mfma_f32_16x16x32_bf16(af1[rt], B.v, acc[rt][st], 0, 0, 0);
        }
    }

    if (ATOMIC) {
#pragma unroll
        for (int rt = 0; rt < 4; rt++)
#pragma unroll
            for (int st = 0; st < 4; st++)
#pragma unroll
                for (int r = 0; r < 4; r++) {
                    int s = w * 64 + st * 16 + rowl;
                    int c = c0b + rt * 16 + g16 * 4 + r;
                    atomicAdd(&outp[((size_t)b * SS + s) * CC + c], acc[rt][st][r]);
                }
    } else {
        float* dst = outp + (size_t)(kc * BB + b) * SS * CC;
#pragma unroll
        for (int rt = 0; rt < 4; rt++)
#pragma unroll
            for (int st = 0; st < 4; st++)
#pragma unroll
                for (int r = 0; r < 4; r++) {
                    int s = w * 64 + st * 16 + rowl;
                    int c = c0b + rt * 16 + g16 * 4 + r;
                    dst[(size_t)s * CC + c] = acc[rt][st][r];
                }
    }
}

// ---------------- K3: bank fp32->bf16 + row norms, float4 vectorized ----------------
__global__ __launch_bounds__(256) void k_cvtmb2(const float* __restrict__ mb,
                                                unsigned short* __restrict__ mbh,
                                                float* __restrict__ yn) {
    int w = threadIdx.x >> 6, l = threadIdx.x & 63;
    int r0 = blockIdx.x * 16 + w * 4;
#pragma unroll
    for (int i = 0; i < 4; i++) {
        int row = r0 + i;
        const float4* src = (const float4*)(mb + (size_t)row * CC);
        float4 a = src[l];
        float4 b2 = {0.f, 0.f, 0.f, 0.f};
        if (l < 32) b2 = src[64 + l];
        ushort4 ua; ua.x = f2bf_rne(a.x); ua.y = f2bf_rne(a.y); ua.z = f2bf_rne(a.z); ua.w = f2bf_rne(a.w);
        ((ushort4*)(mbh + (size_t)row * CC))[l] = ua;
        if (l < 32) {
            ushort4 ub; ub.x = f2bf_rne(b2.x); ub.y = f2bf_rne(b2.y); ub.z = f2bf_rne(b2.z); ub.w = f2bf_rne(b2.w);
            ((ushort4*)(mbh + (size_t)row * CC))[64 + l] = ub;
        }
        float s = a.x * a.x + a.y * a.y + a.z * a.z + a.w * a.w
                + b2.x * b2.x + b2.y * b2.y + b2.z * b2.z + b2.w * b2.w;
#pragma unroll
        for (int m = 32; m; m >>= 1) s += __shfl_xor(s, m);
        if (l == 0) yn[row] = s;
    }
}

__global__ __launch_bounds__(256) void k_ynorm2(const float* __restrict__ mb, float* __restrict__ yn) {
    int w = threadIdx.x >> 6, l = threadIdx.x & 63;
    int r0 = blockIdx.x * 16 + w * 4;
#pragma unroll
    for (int i = 0; i < 4; i++) {
        int row = r0 + i;
        const float4* src = (const float4*)(mb + (size_t)row * CC);
        float4 a = src[l];
        float4 b2 = {0.f, 0.f, 0.f, 0.f};
        if (l < 32) b2 = src[64 + l];
        float s = a.x * a.x + a.y * a.y + a.z * a.z + a.w * a.w
                + b2.x * b2.x + b2.y * b2.y + b2.z * b2.z + b2.w * b2.w;
#pragma unroll
        for (int m = 32; m; m >>= 1) s += __shfl_xor(s, m);
        if (l == 0) yn[row] = s;
    }
}

// ---------------- K4a: reduce kc-partials + counts -> emb/xn/embh ----------------
__global__ __launch_bounds__(256) void k_embfin3(const float* __restrict__ kcpart,
                                                 const unsigned* __restrict__ cntS,
                                                 float* __restrict__ emb, float* __restrict__ xn,
                                                 unsigned short* __restrict__ embh) {
    int w = threadIdx.x >> 6, l = threadIdx.x & 63;
    int i = blockIdx.x * 4 + w;
    int b = i >> 8, s256 = i & 255;
    float4 a0 = {0.f, 0.f, 0.f, 0.f}, a1 = {0.f, 0.f, 0.f, 0.f};
#pragma unroll 4
    for (int kc = 0; kc < NKC; kc++) {
        const float4* row = (const float4*)(kcpart + ((size_t)(kc * BB + b) * SS + s256) * CC);
        float4 v = row[l];
        a0.x += v.x; a0.y += v.y; a0.z += v.z; a0.w += v.w;
        if (l < 32) {
            float4 v1 = row[64 + l];
            a1.x += v1.x; a1.y += v1.y; a1.z += v1.z; a1.w += v1.w;
        }
    }
    float cw = (l < 49) ? (float)cntS[(l * BB + b) * SS + s256] : 0.f;
#pragma unroll
    for (int m = 32; m; m >>= 1) cw += __shfl_xor(cw, m);
    float inv = 1.f / fmaxf(cw, 1.f);

    a0.x *= inv; a0.y *= inv; a0.z *= inv; a0.w *= inv;
    a1.x *= inv; a1.y *= inv; a1.z *= inv; a1.w *= inv;
    ((float4*)(emb + (size_t)i * CC))[l] = a0;
    ushort4 u0; u0.x = f2bf_rne(a0.x); u0.y = f2bf_rne(a0.y); u0.z = f2bf_rne(a0.z); u0.w = f2bf_rne(a0.w);
    ((ushort4*)(embh + (size_t)i * CC))[l] = u0;
    if (l < 32) {
        ((float4*)(emb + (size_t)i * CC))[64 + l] = a1;
        ushort4 u1; u1.x = f2bf_rne(a1.x); u1.y = f2bf_rne(a1.y); u1.z = f2bf_rne(a1.z); u1.w = f2bf_rne(a1.w);
        ((ushort4*)(embh + (size_t)i * CC))[64 + l] = u1;
    }
    float ss = a0.x * a0.x + a0.y * a0.y + a0.z * a0.z + a0.w * a0.w
             + a1.x * a1.x + a1.y * a1.y + a1.z * a1.z + a1.w * a1.w;
#pragma unroll
    for (int m = 32; m; m >>= 1) ss += __shfl_xor(ss, m);
    if (l == 0) xn[i] = ss;
}

// ---------------- K4b: finalize emb in place (lowmem path) ----------------
__global__ __launch_bounds__(256) void k_embfin_lm(float* __restrict__ emb,
                                                   const unsigned* __restrict__ cntS,
                                                   float* __restrict__ xn,
                                                   unsigned short* __restrict__ embh) {
    int w = threadIdx.x >> 6, l = threadIdx.x & 63;
    int i = blockIdx.x * 4 + w;
    int b = i >> 8, s256 = i & 255;
    float4* e4 = (float4*)(emb + (size_t)i * CC);
    float4 a0 = e4[l];
    float4 a1 = {0.f, 0.f, 0.f, 0.f};
    if (l < 32) a1 = e4[64 + l];
    float cw = (l < 49) ? (float)cntS[(l * BB + b) * SS + s256] : 0.f;
#pragma unroll
    for (int m = 32; m; m >>= 1) cw += __shfl_xor(cw, m);
    float inv = 1.f / fmaxf(cw, 1.f);
    a0.x *= inv; a0.y *= inv; a0.z *= inv; a0.w *= inv;
    a1.x *= inv; a1.y *= inv; a1.z *= inv; a1.w *= inv;
    e4[l] = a0;
    ushort4 u0; u0.x = f2bf_rne(a0.x); u0.y = f2bf_rne(a0.y); u0.z = f2bf_rne(a0.z); u0.w = f2bf_rne(a0.w);
    ((ushort4*)(embh + (size_t)i * CC))[l] = u0;
    if (l < 32) {
        e4[64 + l] = a1;
        ushort4 u1; u1.x = f2bf_rne(a1.x); u1.y = f2bf_rne(a1.y); u1.z = f2bf_rne(a1.z); u1.w = f2bf_rne(a1.w);
        ((ushort4*)(embh + (size_t)i * CC))[64 + l] = u1;
    }
    float ss = a0.x * a0.x + a0.y * a0.y + a0.z * a0.z + a0.w * a0.w
             + a1.x * a1.x + a1.y * a1.y + a1.z * a1.z + a1.w * a1.w;
#pragma unroll
    for (int m = 32; m; m >>= 1) ss += __shfl_xor(ss, m);
    if (l == 0) xn[i] = ss;
}

// ---------------- K5: 128x128 bf16 MFMA GEMM + fused row-min (u32 keys) ----------------
template <bool REGB>
__global__ __launch_bounds__(256) void k_gemm(
        const unsigned short* __restrict__ Ah, const unsigned short* __restrict__ Bh,
        const float* __restrict__ Bf,
        const float* __restrict__ xn, const float* __restrict__ yn,
        unsigned* __restrict__ partials) {
    __shared__ bf16x8 As[8][128];
    __shared__ bf16x8 Bs[8][128];
    __shared__ unsigned rowbest[128];
    int bid = blockIdx.x;
    int swz = (bid & 7) * 1024 + (bid >> 3);
    int rb = swz & 15, nb = swz >> 4;
    int t = threadIdx.x;
    int w = t >> 6, l = t & 63;
    int wm = w & 1, wn = w >> 1;

    if (t < 128) rowbest[t] = 0xFFFFFFFFu;

    fx16 acc00, acc01, acc10, acc11;
#pragma unroll
    for (int p = 0; p < 16; p++) { acc00[p] = 0.f; acc01[p] = 0.f; acc10[p] = 0.f; acc11[p] = 0.f; }

    const unsigned short* Abase = Ah + (size_t)(rb * 128) * CC;
    const unsigned short* Bbase = REGB ? nullptr : (Bh + (size_t)(nb * 128) * CC);
    const float* Bfbase = Bf + (size_t)(nb * 128) * CC;

    for (int kt = 0; kt < 6; kt++) {
        int k0 = kt * 64;
#pragma unroll
        for (int q = 0; q < 4; q++) {
            int c = q * 256 + t;
            int r = c & 127, g = c >> 7;
            gl_lds16(Abase + (size_t)r * CC + k0 + g * 8, &As[g][r]);
            if (!REGB) {
                gl_lds16(Bbase + (size_t)r * CC + k0 + g * 8, &Bs[g][r]);
            } else {
                const float* src = Bfbase + (size_t)r * CC + k0 + g * 8;
                float4 v0 = *(const float4*)(src);
                float4 v1 = *(const float4*)(src + 4);
                Bs[g][r] = pack8(v0, v1);
            }
        }
        __syncthreads();
#pragma unroll
        for (int s = 0; s < 4; s++) {
            int g = s * 2 + (l >> 5);
            bf16x8 a0 = As[g][wm * 64 + (l & 31)];
            bf16x8 a1 = As[g][wm * 64 + 32 + (l & 31)];
            bf16x8 b0 = Bs[g][wn * 64 + (l & 31)];
            bf16x8 b1 = Bs[g][wn * 64 + 32 + (l & 31)];
            acc00 = __builtin_amdgcn_mfma_f32_32x32x16_bf16(a0, b0, acc00, 0, 0, 0);
            acc01 = __builtin_amdgcn_mfma_f32_32x32x16_bf16(a0, b1, acc01, 0, 0, 0);
            acc10 = __builtin_amdgcn_mfma_f32_32x32x16_bf16(a1, b0, acc10, 0, 0, 0);
            acc11 = __builtin_amdgcn_mfma_f32_32x32x16_bf16(a1, b1, acc11, 0, 0, 0);
        }
        __syncthreads();
    }

    int coll0 = wn * 64 + (l & 31);
    int coll1 = coll0 + 32;
    float yn0 = yn[nb * 128 + coll0], yn1 = yn[nb * 128 + coll1];
#pragma unroll
    for (int i = 0; i < 2; i++) {
#pragma unroll
        for (int p = 0; p < 16; p++) {
            float a0v = (i == 0) ? acc00[p] : acc10[p];
            float a1v = (i == 0) ? acc01[p] : acc11[p];
            int rl = i * 32 + (p & 3) + 8 * (p >> 2) + 4 * (l >> 5);
            float xr = xn[rb * 128 + wm * 64 + rl];
            float d0 = fmaxf(xr - 2.f * a0v + yn0, 0.f);
            float d1 = fmaxf(xr - 2.f * a1v + yn1, 0.f);
            unsigned k0 = (__float_as_uint(d0) & 0xFFFFFF00u) | (unsigned)coll0;
            unsigned k1 = (__float_as_uint(d1) & 0xFFFFFF00u) | (unsigned)coll1;
            unsigned best = k0 < k1 ? k0 : k1;
#pragma unroll
            for (int m = 1; m < 32; m <<= 1) {
                unsigned o2 = __shfl_xor(best, m);
                if (o2 < best) best = o2;
            }
            if ((l & 31) == 0) atomicMin(&rowbest[wm * 64 + rl], best);
        }
    }
    __syncthreads();
    if (t < 128) partials[(size_t)nb * GM + rb * 128 + t] = rowbest[t];
}

// ---------------- K6: expand u32 keys -> u64 global, min over 64 nb ----------------
__global__ void k_reduce1(const unsigned* __restrict__ partials,
                          unsigned long long* __restrict__ partial2) {
    int row = blockIdx.x * 256 + threadIdx.x;
    int ng = blockIdx.y;
    unsigned long long m = ~0ull;
    for (int n = 0; n < 64; n++) {
        int nb = ng * 64 + n;
        unsigned k = partials[(size_t)nb * GM + row];
        unsigned long long v = ((unsigned long long)(k & 0xFFFFFF00u) << 32)
                             | (unsigned)(nb * 128 + (k & 0xFFu));
        if (v < m) m = v;
    }
    partial2[ng * GM + row] = m;
}

// ---------------- K7: final min + scores + per-batch top-4 candidates ----------------
__global__ void k_reduce2cand(const unsigned long long* __restrict__ partial2,
                              float* __restrict__ scores, int* __restrict__ locs,
                              int* __restrict__ cand) {
    __shared__ unsigned long long key[256];
    __shared__ unsigned long long red[256];
    int b = blockIdx.x, t = threadIdx.x;
    int row = b * 256 + t;
    unsigned long long m = ~0ull;
    for (int g = 0; g < 8; g++) {
        unsigned long long v = partial2[g * GM + row];
        if (v < m) m = v;
    }
    float sc = sqrtf(__uint_as_float((unsigned)(m >> 32)));
    scores[row] = sc;
    locs[row] = (int)(m & 0xffffffffu);
    key[t] = ((unsigned long long)__float_as_uint(sc) << 32) | (unsigned)(255 - t);
    __syncthreads();
    for (int k = 0; k < 4; k++) {
        red[t] = key[t];
        __syncthreads();
        for (int s = 128; s; s >>= 1) {
            if (t < s && red[t + s] > red[t]) red[t] = red[t + s];
            __syncthreads();
        }
        unsigned long long win = red[0];
        int patch = 255 - (int)(win & 0xffffffffu);
        if (t == 0) cand[b * 4 + k] = b * SS + patch;
        __syncthreads();
        if (t == patch) key[t] = 0;
        __syncthreads();
    }
}

// ---------------- K9: exact fp32 re-search — lane-owns-candidate serial dots ----------------
// clT[k][j] transposed in LDS: lane j reads bank j (conflict-free; half-waves broadcast).
// Lane j keeps candidate j's running min in a register -> zero shuffles, zero LDS atomics.
__global__ __launch_bounds__(256) void k_refine3(
        const float* __restrict__ emb, const float* __restrict__ mb,
        const float* __restrict__ xn, const float* __restrict__ yn,
        const int* __restrict__ cand, unsigned long long* __restrict__ refpart) {
    __shared__ float clT[CC][32];        // 48 KB
    __shared__ float xnc[32];
    __shared__ int cr[32];
    __shared__ unsigned long long wbest[4][64];
    int t = threadIdx.x, w = t >> 6, l = t & 63;
    if (t < 32) cr[t] = cand[t];
    __syncthreads();
    if (t < 32) xnc[t] = xn[cr[t]];
    {
        int j = t & 31;
        int r = cr[j];
        for (int kk = t >> 5; kk < CC; kk += 8)
            clT[kk][j] = emb[(size_t)r * CC + kk];
    }
    __syncthreads();

    int j = l & 31;
    int half = l >> 5;
    unsigned long long best = ~0ull;
#pragma unroll
    for (int pr = 0; pr < 8; pr++) {
        int m = blockIdx.x * 64 + w * 16 + pr * 2 + half;
        const float4* r4 = (const float4*)(mb + (size_t)m * CC);
        float s = 0.f;
#pragma unroll 8
        for (int k4 = 0; k4 < CC / 4; k4++) {
            float4 v = r4[k4];
            s = fmaf(v.x, clT[k4 * 4 + 0][j], s);
            s = fmaf(v.y, clT[k4 * 4 + 1][j], s);
            s = fmaf(v.z, clT[k4 * 4 + 2][j], s);
            s = fmaf(v.w, clT[k4 * 4 + 3][j], s);
        }
        float d2 = fmaxf(xnc[j] - 2.f * s + yn[m], 0.f);
        unsigned long long key = ((unsigned long long)__float_as_uint(d2) << 32) | (unsigned)m;
        if (key < best) best = key;
    }
    wbest[w][l] = best;
    __syncthreads();
    if (t < 32) {
        unsigned long long m = ~0ull;
#pragma unroll
        for (int ww = 0; ww < 4; ww++) {
            if (wbest[ww][t] < m) m = wbest[ww][t];
            if (wbest[ww][t + 32] < m) m = wbest[ww][t + 32];
        }
        refpart[(size_t)blockIdx.x * 32 + t] = m;
    }
}

__global__ void k_refred(const unsigned long long* __restrict__ refpart,
                         unsigned long long* __restrict__ keys2) {
    __shared__ unsigned long long red[256];
    int j = blockIdx.x, t = threadIdx.x;
    unsigned long long m = ~0ull;
    for (int i = t; i < RFB3; i += 256) {
        unsigned long long v = refpart[(size_t)i * 32 + j];
        if (v < m) m = v;
    }
    red[t] = m;
    __syncthreads();
    for (int s = 128; s; s >>= 1) {
        if (t < s && red[t + s] < red[t]) red[t] = red[t + s];
        __syncthreads();
    }
    if (t == 0) keys2[j] = red[0];
}

__global__ void k_final(const unsigned long long* __restrict__ keys2, const int* __restrict__ cand,
                        int* __restrict__ mp, float* __restrict__ scb, int* __restrict__ nn) {
    int b = threadIdx.x;
    if (b < BB) {
        float bestsc = -1.f;
        int bestpatch = 1 << 20, bestnn = 0;
        for (int k = 0; k < 4; k++) {
            unsigned long long key = keys2[b * 4 + k];
            float sc = sqrtf(__uint_as_float((unsigned)(key >> 32)));
            int patch = cand[b * 4 + k] & 255;
            int nnidx = (int)(key & 0xffffffffu);
            if (sc > bestsc || (sc == bestsc && patch < bestpatch)) {
                bestsc = sc; bestpatch = patch; bestnn = nnidx;
            }
        }
        mp[b] = bestpatch; scb[b] = bestsc; nn[b] = bestnn;
    }
}

// ---------------- K12: d_nn — lane-owns-(b,m) serial dots ----------------
// nnT[k4][b] float4 in LDS: 8 distinct 16B slots = all 32 banks, conflict-free.
__global__ __launch_bounds__(256) void k_dnn3(const float* __restrict__ mb,
                                              const float* __restrict__ yn,
                                              const int* __restrict__ nn,
                                              float* __restrict__ dnn) {
    __shared__ float4 nnT[CC / 4][BB];   // 12 KB
    __shared__ float ynn[BB];
    int t = threadIdx.x, w = t >> 6, l = t & 63;
    for (int i = t; i < (CC / 4) * BB; i += 256) {
        int k4 = i >> 3, b = i & 7;
        nnT[k4][b] = ((const float4*)(mb + (size_t)nn[b] * CC))[k4];
    }
    if (t < BB) ynn[t] = yn[nn[t]];
    __syncthreads();

    int b = l & 7, mg = l >> 3;
    int m = blockIdx.x * 32 + w * 8 + mg;
    const float4* r4 = (const float4*)(mb + (size_t)m * CC);
    float s = 0.f;
#pragma unroll 8
    for (int k4 = 0; k4 < CC / 4; k4++) {
        float4 v = r4[k4];
        float4 n = nnT[k4][b];
        s = fmaf(v.x, n.x, s);
        s = fmaf(v.y, n.y, s);
        s = fmaf(v.z, n.z, s);
        s = fmaf(v.w, n.w, s);
    }
    float d2 = fmaxf(ynn[b] - 2.f * s + yn[m], 0.f);
    dnn[(size_t)b * MM + m] = sqrtf(d2);
}

// ---------------- K13a: per-chunk top-9 (64 chunks x 8 batches) ----------------
__global__ void k_top9a(const float* __restrict__ dnn, float* __restrict__ t9v,
                        int* __restrict__ t9i) {
    __shared__ float sd[256][TOPK];
    __shared__ int sx[256][TOPK];
    int c = blockIdx.x, b = blockIdx.y, t = threadIdx.x;
    float ld[TOPK];
    int li[TOPK];
#pragma unroll
    for (int k = 0; k < TOPK; k++) { ld[k] = INFINITY; li[k] = MM; }
    const float* d = dnn + (size_t)b * MM;
    for (int m = c * 1024 + t; m < (c + 1) * 1024; m += 256) {
        float v = d[m];
        if (v < ld[TOPK - 1] || (v == ld[TOPK - 1] && m < li[TOPK - 1])) {
            int k = TOPK - 1;
            while (k > 0 && (v < ld[k - 1] || (v == ld[k - 1] && m < li[k - 1]))) {
                ld[k] = ld[k - 1]; li[k] = li[k - 1]; k--;
            }
            ld[k] = v; li[k] = m;
        }
    }
    for (int k = 0; k < TOPK; k++) { sd[t][k] = ld[k]; sx[t][k] = li[k]; }
    __syncthreads();
    for (int s = 128; s; s >>= 1) {
        if (t < s) {
            float md[TOPK]; int mi[TOPK];
            int p = 0, q = 0;
            for (int k = 0; k < TOPK; k++) {
                float va = sd[t][p], vb = sd[t + s][q];
                int ia = sx[t][p], ib = sx[t + s][q];
                bool ta = (va < vb) || (va == vb && ia < ib);
                if (ta) { md[k] = va; mi[k] = ia; p++; }
                else    { md[k] = vb; mi[k] = ib; q++; }
            }
            for (int k = 0; k < TOPK; k++) { sd[t][k] = md[k]; sx[t][k] = mi[k]; }
        }
        __syncthreads();
    }
    if (t < TOPK) {
        t9v[(b * 64 + c) * TOPK + t] = sd[0][t];
        t9i[(b * 64 + c) * TOPK + t] = sx[0][t];
    }
}

// ---------------- K13b+K14: merge top-9 + pred_score (fused) ----------------
__global__ void k_fintop(const float* __restrict__ t9v, const int* __restrict__ t9i,
                         const float* __restrict__ emb, const float* __restrict__ mb,
                         const float* __restrict__ yn, const float* __restrict__ xn,
                         const int* __restrict__ mp, const float* __restrict__ scb,
                         float* __restrict__ outp) {
    __shared__ float sd[256][TOPK];
    __shared__ int sx[256][TOPK];
    __shared__ int supl[TOPK];
    __shared__ float ds[TOPK];
    int b = blockIdx.x, t = threadIdx.x;
    float ld[TOPK];
    int li[TOPK];
#pragma unroll
    for (int k = 0; k < TOPK; k++) { ld[k] = INFINITY; li[k] = MM; }
    for (int i = t; i < 64 * TOPK; i += 256) {
        float v = t9v[b * 64 * TOPK + i];
        int m = t9i[b * 64 * TOPK + i];
        if (v < ld[TOPK - 1] || (v == ld[TOPK - 1] && m < li[TOPK - 1])) {
            int k = TOPK - 1;
            while (k > 0 && (v < ld[k - 1] || (v == ld[k - 1] && m < li[k - 1]))) {
                ld[k] = ld[k - 1]; li[k] = li[k - 1]; k--;
            }
            ld[k] = v; li[k] = m;
        }
    }
    for (int k = 0; k < TOPK; k++) { sd[t][k] = ld[k]; sx[t][k] = li[k]; }
    __syncthreads();
    for (int s = 128; s; s >>= 1) {
        if (t < s) {
            float md[TOPK]; int mi[TOPK];
            int p = 0, q = 0;
            for (int k = 0; k < TOPK; k++) {
                float va = sd[t][p], vb = sd[t + s][q];
                int ia = sx[t][p], ib = sx[t + s][q];
                bool ta = (va < vb) || (va == vb && ia < ib);
                if (ta) { md[k] = va; mi[k] = ia; p++; }
                else    { md[k] = vb; mi[k] = ib; q++; }
            }
            for (int k = 0; k < TOPK; k++) { sd[t][k] = md[k]; sx[t][k] = mi[k]; }
        }
        __syncthreads();
    }
    if (t < TOPK) supl[t] = sx[0][t];
    __syncthreads();

    int w = t >> 6, l = t & 63;
    int mpb = mp[b];
    const float* mf = emb + ((size_t)b * SS + mpb) * CC;
    float xr = xn[b * SS + mpb];
    for (int k = w; k < TOPK; k += 4) {
        int sidx = supl[k];
        const float* sr = mb + (size_t)sidx * CC;
        float s = 0.f;
#pragma unroll
        for (int i = 0; i < 6; i++) s = fmaf(mf[i * 64 + l], sr[i * 64 + l], s);
#pragma unroll
        for (int mm = 32; mm; mm >>= 1) s += __shfl_xor(s, mm);
        if (l == 0) ds[k] = sqrtf(fmaxf(xr - 2.f * s + yn[sidx], 0.f));
    }
    __syncthreads();
    if (t == 0) {
        float mx = ds[0];
        for (int k = 1; k < TOPK; k++) mx = fmaxf(mx, ds[k]);
        float num = expf(ds[0] - mx), den = 0.f;
        for (int k = 0; k < TOPK; k++) den += expf(ds[k] - mx);
        outp[b] = (1.f - num / den) * scb[b];
    }
}

// ---------------- K15: anomaly map scatter (int4/float4) ----------------
__global__ void k_map4(const float* __restrict__ scores, const int* __restrict__ labels,
                       float* __restrict__ out) {
    size_t i4 = (size_t)blockIdx.x * 256 + threadIdx.x;
    int b = (int)(i4 / (HWP / 4));
    int4 lv = ((const int4*)labels)[i4];
    const float* sb = scores + b * SS;
    float4 o;
    o.x = sb[lv.x]; o.y = sb[lv.y]; o.z = sb[lv.z]; o.w = sb[lv.w];
    ((float4*)out)[i4] = o;
}

extern "C" void kernel_launch(void* const* d_in, const int* in_sizes, int n_in,
                              void* d_out, int out_size, void* d_ws, size_t ws_size,
                              hipStream_t stream) {
    const float* feats  = (const float*)d_in[0];
    const int*   labels = (const int*)d_in[1];
    const float* mb     = (const float*)d_in[2];
    float* out = (float*)d_out;

    char* ws = (char*)d_ws;
    const size_t SZ_MBH   = (size_t)MM * CC * 2;              // 50.3 MB
    const size_t SZ_EMBH  = (size_t)GM * CC * 2;
    const size_t SZ_EMB   = (size_t)GM * CC * 4;
    const size_t SZ_YN    = (size_t)MM * 4;
    const size_t SZ_SMALL = 8192;
    const size_t SZ_CNTS  = (size_t)49 * BB * SS * 4;         // 401 KB
    const size_t SZ_P2    = (size_t)8 * GM * 8;
    const size_t SZ_T9    = (size_t)BB * 64 * TOPK * 4;
    const size_t SZ_KCP   = (size_t)NKC * BB * SS * CC * 4;   // 50.3 MB
    const size_t SZ_BIG   = SZ_KCP;

    size_t need_full = SZ_MBH + SZ_EMBH + SZ_EMB + SZ_YN + 3 * SZ_SMALL + SZ_CNTS + 2048
                     + SZ_P2 + 2 * SZ_T9 + SZ_BIG + 1024;
    bool lowmem = ws_size < need_full;

    size_t o = 0;
    unsigned short* mbh = nullptr;
    if (!lowmem) { mbh = (unsigned short*)(ws + o); o += SZ_MBH; }
    unsigned short* embh = (unsigned short*)(ws + o); o += SZ_EMBH;
    float* emb = (float*)(ws + o);                    o += SZ_EMB;
    float* yn  = (float*)(ws + o);                    o += SZ_YN;
    float* xn  = (float*)(ws + o);                    o += SZ_SMALL;
    float* scores = (float*)(ws + o);                 o += SZ_SMALL;
    int*   locs   = (int*)(ws + o);                   o += SZ_SMALL;
    unsigned* cntS = (unsigned*)(ws + o);             o += SZ_CNTS;
    int*   cand   = (int*)(ws + o);                   o += 256;
    unsigned long long* keys2 = (unsigned long long*)(ws + o); o += 256;
    int*   mp  = (int*)(ws + o);                      o += 128;
    float* scb = (float*)(ws + o);                    o += 128;
    int*   nn  = (int*)(ws + o);                      o += 128;
    o = (o + 255) & ~(size_t)255;
    float* t9v = (float*)(ws + o);                    o += SZ_T9;
    int*   t9i = (int*)(ws + o);                      o += SZ_T9;
    o = (o + 255) & ~(size_t)255;
    unsigned long long* partial2 = (unsigned long long*)(ws + o); o += SZ_P2;
    char* big = ws + o;
    float* kcpart = (float*)big;                                   // segsum partials
    unsigned* partials = (unsigned*)big;                           // gemm u32 partials (after kcpart dead)
    unsigned long long* refpart  = (unsigned long long*)big;       // after partials consumed (256 KB)
    float* dnn = (float*)(big + 4194304);                          // disjoint from refpart

    k_counts3<<<dim3(49, BB), 256, 0, stream>>>(labels, cntS);

    if (!lowmem) {
        k_segsum7<false><<<dim3(NKC, 6, BB), 256, 0, stream>>>(feats, labels, kcpart);
        k_cvtmb2<<<MM / 16, 256, 0, stream>>>(mb, mbh, yn);
        k_embfin3<<<GM / 4, 256, 0, stream>>>(kcpart, cntS, emb, xn, embh);
        k_gemm<false><<<8192, 256, 0, stream>>>(embh, mbh, mb, xn, yn, partials);
    } else {
        hipMemsetAsync(emb, 0, SZ_EMB, stream);
        k_segsum7<true><<<dim3(NKC, 6, BB), 256, 0, stream>>>(feats, labels, emb);
        k_ynorm2<<<MM / 16, 256, 0, stream>>>(mb, yn);
        k_embfin_lm<<<GM / 4, 256, 0, stream>>>(emb, cntS, xn, embh);
        k_gemm<true><<<8192, 256, 0, stream>>>(embh, embh, mb, xn, yn, partials);
    }

    k_reduce1<<<dim3(8, 8), 256, 0, stream>>>(partials, partial2);
    k_reduce2cand<<<BB, 256, 0, stream>>>(partial2, scores, locs, cand);
    k_refine3<<<RFB3, 256, 0, stream>>>(emb, mb, xn, yn, cand, refpart);
    k_refred<<<32, 256, 0, stream>>>(refpart, keys2);
    k_final<<<1, 64, 0, stream>>>(keys2, cand, mp, scb, nn);
    k_dnn3<<<MM / 32, 256, 0, stream>>>(mb, yn, nn, dnn);
    k_top9a<<<dim3(64, BB), 256, 0, stream>>>(dnn, t9v, t9i);
    k_fintop<<<BB, 256, 0, stream>>>(t9v, t9i, emb, mb, yn, xn, mp, scb, out + (size_t)BB * HWP);
    k_map4<<<(BB * HWP / 4) / 256, 256, 0, stream>>>(scores, labels, out);
}